// Round 4
// baseline (620.434 us; speedup 1.0000x reference)
//
#include <hip/hip_runtime.h>
#include <hip/hip_bf16.h>
#include <cstddef>

// ---------------------------------------------------------------------------
// Constants for this problem: B=4, L=2048, D=1024
// ---------------------------------------------------------------------------
#define BB 4
#define LL 2048
#define DD 1024
#define MM (BB*LL)          // 8192 tokens
#define KF_STRIDE 2056      // complex elements per Kf row (>= 2049, 16B-aligned)

// LDS bank swizzle for float2 arrays: spreads Stockham write streams across
// bank-pairs. Modifies bits 2-3 only (stays in range).
#define SWZ(a) ((a) ^ (((a) >> 4) & 12))

typedef __bf16 bf16_t;
typedef __attribute__((ext_vector_type(8))) __bf16 bf16x8;
typedef __attribute__((ext_vector_type(4))) __bf16 bf16x4;
typedef __attribute__((ext_vector_type(4))) float f32x4;

// async global->LDS, 16 bytes per lane (global_load_lds_dwordx4)
#define GLD_LDS16(gp, lp) __builtin_amdgcn_global_load_lds(                 \
    (const __attribute__((address_space(1))) unsigned int*)(gp),            \
    (__attribute__((address_space(3))) unsigned int*)(lp), 16, 0, 0)

// raw barrier + compile-time fence (rule #18: keep hipcc from hoisting
// LDS reads / MFMA across raw s_barrier + inline-asm waitcnt)
#define BARX() do { __builtin_amdgcn_s_barrier();                           \
                    __builtin_amdgcn_sched_barrier(0); } while (0)
#define VMW(N) asm volatile("s_waitcnt vmcnt(" #N ")" ::: "memory")

__device__ __forceinline__ float gelu_tanh(float x) {
    const float c = 0.7978845608028654f;   // sqrt(2/pi)
    float t = tanhf(c * (x + 0.044715f * x * x * x));
    return 0.5f * x * (1.0f + t);
}

__device__ __forceinline__ float2 cmul(float2 a, float2 b) {
    return make_float2(a.x * b.x - a.y * b.y, a.x * b.y + a.y * b.x);
}
__device__ __forceinline__ float2 cadd(float2 a, float2 b) {
    return make_float2(a.x + b.x, a.y + b.y);
}
__device__ __forceinline__ float2 csub(float2 a, float2 b) {
    return make_float2(a.x - b.x, a.y - b.y);
}
// multiply by i*sigma (sigma = +-1)
__device__ __forceinline__ float2 cmuli(float2 z, float s) {
    return make_float2(-s * z.y, s * z.x);
}

// ---------------------------------------------------------------------------
// fp32 -> bf16 cast of all 4 weight matrices in ONE launch.
// ---------------------------------------------------------------------------
__global__ __launch_bounds__(256) void cast_all_kernel(
    const float* __restrict__ s0, const float* __restrict__ s1,
    const float* __restrict__ s2, const float* __restrict__ s3,
    bf16_t* __restrict__ d0, bf16_t* __restrict__ d1,
    bf16_t* __restrict__ d2, bf16_t* __restrict__ d3)
{
    const int b = blockIdx.x;
    const float* s; bf16_t* d; int base;
    if (b < 3072)      { s = s0; d = d0; base = b; }
    else if (b < 4096) { s = s1; d = d1; base = b - 3072; }
    else if (b < 6144) { s = s2; d = d2; base = b - 4096; }
    else               { s = s3; d = d3; base = b - 6144; }
    const int i = (base * 256 + threadIdx.x) * 4;
    const float4 v = *(const float4*)(s + i);
    bf16x4 o;
    o[0] = (bf16_t)v.x; o[1] = (bf16_t)v.y; o[2] = (bf16_t)v.z; o[3] = (bf16_t)v.w;
    *(bf16x4*)(d + i) = o;
}

// ---------------------------------------------------------------------------
// RMSNorm -> bf16 output: one block per row of 1024 floats
// ---------------------------------------------------------------------------
__global__ __launch_bounds__(256) void rmsnorm_bf16_kernel(
    const float* __restrict__ in, const float* __restrict__ w,
    bf16_t* __restrict__ out)
{
    const int row = blockIdx.x;
    const float4* ip = (const float4*)(in + (size_t)row * DD);
    float4 v = ip[threadIdx.x];
    float ss = v.x*v.x + v.y*v.y + v.z*v.z + v.w*v.w;
    #pragma unroll
    for (int off = 32; off > 0; off >>= 1) ss += __shfl_down(ss, off, 64);
    __shared__ float sums[4];
    const int wid = threadIdx.x >> 6;
    if ((threadIdx.x & 63) == 0) sums[wid] = ss;
    __syncthreads();
    const float tot = sums[0] + sums[1] + sums[2] + sums[3];
    const float scale = rsqrtf(tot * (1.0f / (float)DD) + 1e-8f);
    const float4 wv = ((const float4*)w)[threadIdx.x];
    bf16x4 o;
    o[0] = (bf16_t)(v.x * scale * wv.x);
    o[1] = (bf16_t)(v.y * scale * wv.y);
    o[2] = (bf16_t)(v.z * scale * wv.z);
    o[3] = (bf16_t)(v.w * scale * wv.w);
    *(bf16x4*)(out + (size_t)row * DD + threadIdx.x * 4) = o;
}

// ---------------------------------------------------------------------------
// 128x128 bf16 MFMA GEMM (2-phase dbuf) -- kept for N=1024 shapes (steps 7,10)
// where a 256^2 grid would idle half the chip.
// ---------------------------------------------------------------------------
template<int EPI, bool BF16OUT, bool BIASROW = false>
__global__ __launch_bounds__(256) void gemm_mfma_kernel(
    const bf16_t* __restrict__ A,    // (M,K)
    const bf16_t* __restrict__ W,    // (N,K)
    const float* __restrict__ bias,  // (N) or (M) if BIASROW
    const float* __restrict__ res,   // (M,N) or nullptr
    float* __restrict__ Cf,          // fp32 out (if !BF16OUT)
    bf16_t* __restrict__ Cb,         // bf16 out (if BF16OUT)
    int M, int N, int K)
{
    __shared__ __align__(16) bf16_t As[2][128 * 64];   // 32 KB
    __shared__ __align__(16) bf16_t Ws[2][128 * 64];   // 32 KB
    const int tid  = threadIdx.x;
    const int bm   = blockIdx.y * 128;
    const int bn   = blockIdx.x * 128;
    const int lane = tid & 63;
    const int wave = tid >> 6;
    const int wr   = (wave >> 1) * 64;
    const int wc   = (wave & 1) * 64;

    int srow[4], sqg[4];
    #pragma unroll
    for (int c = 0; c < 4; ++c) {
        const int p = c * 256 + tid;
        srow[c] = p >> 3;
        sqg[c]  = (((p & 7) ^ (srow[c] & 7)) << 3);
    }

    f32x4 acc[4][4] = {};

    const int fr = lane & 15;
    const int fc = (lane >> 4) * 8;

    const int nt = K >> 6;

    #pragma unroll
    for (int c = 0; c < 4; ++c) {
        GLD_LDS16(A + (size_t)(bm + srow[c]) * K + sqg[c],
                  &As[0][c * 2048 + tid * 8]);
        GLD_LDS16(W + (size_t)(bn + srow[c]) * K + sqg[c],
                  &Ws[0][c * 2048 + tid * 8]);
    }
    __syncthreads();

    int cur = 0;
    for (int t = 0; t < nt; ++t) {
        if (t + 1 < nt) {
            const int k0 = (t + 1) << 6;
            #pragma unroll
            for (int c = 0; c < 4; ++c) {
                GLD_LDS16(A + (size_t)(bm + srow[c]) * K + k0 + sqg[c],
                          &As[cur ^ 1][c * 2048 + tid * 8]);
                GLD_LDS16(W + (size_t)(bn + srow[c]) * K + k0 + sqg[c],
                          &Ws[cur ^ 1][c * 2048 + tid * 8]);
            }
        }
        #pragma unroll
        for (int ks = 0; ks < 64; ks += 32) {
            const int q = (ks + fc) >> 3;
            bf16x8 af[4], wf[4];
            #pragma unroll
            for (int i = 0; i < 4; ++i) {
                const int r = wr + i*16 + fr;
                af[i] = *(const bf16x8*)(&As[cur][r * 64 + ((q ^ (r & 7)) << 3)]);
            }
            #pragma unroll
            for (int j = 0; j < 4; ++j) {
                const int r = wc + j*16 + fr;
                wf[j] = *(const bf16x8*)(&Ws[cur][r * 64 + ((q ^ (r & 7)) << 3)]);
            }
            __builtin_amdgcn_s_setprio(1);
            #pragma unroll
            for (int i = 0; i < 4; ++i)
                #pragma unroll
                for (int j = 0; j < 4; ++j)
                    acc[i][j] = __builtin_amdgcn_mfma_f32_16x16x32_bf16(
                        af[i], wf[j], acc[i][j], 0, 0, 0);
            __builtin_amdgcn_s_setprio(0);
        }
        __syncthreads();
        cur ^= 1;
    }

    const int fq = lane >> 4;
    #pragma unroll
    for (int i = 0; i < 4; ++i) {
        const int row0 = bm + wr + i*16 + fq*4;
        #pragma unroll
        for (int j = 0; j < 4; ++j) {
            const int col = bn + wc + j*16 + fr;
            const float bcol = BIASROW ? 0.0f : bias[col];
            #pragma unroll
            for (int r = 0; r < 4; ++r) {
                float v = acc[i][j][r] + (BIASROW ? bias[row0 + r] : bcol);
                if constexpr (EPI == 2) v = gelu_tanh(v);
                if constexpr (EPI == 1) v += res[(size_t)(row0 + r) * N + col];
                if constexpr (BF16OUT)
                    Cb[(size_t)(row0 + r) * N + col] = (bf16_t)v;
                else
                    Cf[(size_t)(row0 + r) * N + col] = v;
            }
        }
    }
}

// ---------------------------------------------------------------------------
// 256x256 bf16 MFMA GEMM -- 8-phase counted-vmcnt schedule (R12 revision).
// R11 failure diagnosed: vmcnt waits had only 1 phase of slack (stage at
// phase p, guarded wait at p+1) -> each wait stalled ~200+ cyc, 3x/K-tile
// ~= the whole K-tile MFMA budget -> MfmaUtil 26%. R12: stage the FULL
// next tile during p0+p1 (2 half-tiles per phase), waits get >=3 phases
// (~450+ cyc) of MFMA cover each:
//   p0: stage A0,B0(t+1); VMW(6)  [guards B1(t), issued 4 phases ago]
//   p1: stage B1,A1(t+1); VMW(8)  [guards A1(t), issued 4 phases ago]
//   p2: --
//   p3: VMW(4)                    [guards A0,B0(t+1), issued 3 phases ago]
// Queue arithmetic (2 vmem instr per half-tile) verified for prologue,
// steady state, and the 8->2->0 drain tail. Raw s_barrier only (never
// __syncthreads = vmcnt(0) drain). Chunk-XOR swizzle (0 bank conflicts).
// ---------------------------------------------------------------------------
__device__ __forceinline__ void stage_half256(
    const bf16_t* __restrict__ G, int grow0, int K, int k0,
    bf16_t* __restrict__ L, int hf, int tid)
{
    #pragma unroll
    for (int cc = 0; cc < 2; ++cc) {
        const int p   = (hf * 2 + cc) * 512 + tid;   // 0..2047
        const int row = p >> 3;                      // 0..255
        const int qg  = (((p & 7) ^ (row & 7)) << 3);
        GLD_LDS16(G + (size_t)(grow0 + row) * K + k0 + qg, L + p * 8);
    }
}

#define LOAD_A256(QR)                                                        \
    _Pragma("unroll")                                                        \
    for (int ks = 0; ks < 2; ++ks)                                           \
      _Pragma("unroll")                                                      \
      for (int mi = 0; mi < 4; ++mi) {                                       \
        const int r = (QR)*128 + vm*64 + mi*16 + fr;                         \
        a[ks][mi] = *(const bf16x8*)(Ac + r*64 + ((((ks*4)+kq) ^ (r&7))<<3)); \
      }

#define LOAD_B256(QC, BV)                                                    \
    _Pragma("unroll")                                                        \
    for (int ks = 0; ks < 2; ++ks)                                           \
      _Pragma("unroll")                                                      \
      for (int nj = 0; nj < 2; ++nj) {                                       \
        const int r = (QC)*128 + vn*32 + nj*16 + fr;                         \
        BV[ks][nj] = *(const bf16x8*)(Wc + r*64 + ((((ks*4)+kq) ^ (r&7))<<3)); \
      }

#define MFMA16(ACC, BV)                                                      \
    __builtin_amdgcn_s_setprio(1);                                           \
    _Pragma("unroll")                                                        \
    for (int ks = 0; ks < 2; ++ks)                                           \
      _Pragma("unroll")                                                      \
      for (int mi = 0; mi < 4; ++mi)                                         \
        _Pragma("unroll")                                                    \
        for (int nj = 0; nj < 2; ++nj)                                       \
          ACC[mi][nj] = __builtin_amdgcn_mfma_f32_16x16x32_bf16(             \
              a[ks][mi], BV[ks][nj], ACC[mi][nj], 0, 0, 0);                  \
    __builtin_amdgcn_s_setprio(0);

template<int EPI, bool BF16OUT, bool BIASROW = false>
__global__ __launch_bounds__(512, 2) void gemm256_kernel(
    const bf16_t* __restrict__ A,    // (M,K)
    const bf16_t* __restrict__ W,    // (N,K)
    const float* __restrict__ bias,  // (N) or (M) if BIASROW
    float* __restrict__ Cf,          // fp32 out (if !BF16OUT)
    bf16_t* __restrict__ Cb,         // bf16 out (if BF16OUT)
    int M, int N, int K)
{
    __shared__ __align__(16) bf16_t As[2][256 * 64];   // 64 KB
    __shared__ __align__(16) bf16_t Ws[2][256 * 64];   // 64 KB
    const int tid  = threadIdx.x;                      // 0..511
    const int bm   = blockIdx.y * 256;
    const int bn   = blockIdx.x * 256;
    const int lane = tid & 63;
    const int wave = tid >> 6;                         // 0..7
    const int vm   = wave >> 2;                        // 0..1 row-group
    const int vn   = wave & 3;                         // 0..3 col-group
    const int fr   = lane & 15;
    const int kq   = lane >> 4;                        // 0..3 k-quad

    bf16x8 a[2][4], b0[2][2], b1[2][2];
    f32x4 acc00[4][2] = {}, acc01[4][2] = {}, acc10[4][2] = {}, acc11[4][2] = {};

    const int nt = K >> 6;                             // >= 2

    // prologue: stage tile0 half-tiles in first-use order [A0,B0,B1,A1]
    stage_half256(A, bm, K, 0, &As[0][0], 0, tid);
    stage_half256(W, bn, K, 0, &Ws[0][0], 0, tid);
    stage_half256(W, bn, K, 0, &Ws[0][0], 1, tid);
    stage_half256(A, bm, K, 0, &As[0][0], 1, tid);
    VMW(4);                       // A0,B0 landed; B1,A1 may be in flight
    BARX();

    for (int t = 0; t < nt - 1; ++t) {
        const int c = t & 1, o = c ^ 1;
        const bf16_t* Ac = &As[c][0];
        const bf16_t* Wc = &Ws[c][0];
        const int kn = (t + 1) << 6;
        // ---- p0: Q(0,0); stage A0,B0(t+1) ----
        LOAD_A256(0); LOAD_B256(0, b0);
        stage_half256(A, bm, K, kn, &As[o][0], 0, tid);
        stage_half256(W, bn, K, kn, &Ws[o][0], 0, tid);
        VMW(6);                          // guards B1(t) (issued 4 phases ago)
        BARX();
        MFMA16(acc00, b0);
        BARX();
        // ---- p1: Q(0,1); stage B1,A1(t+1) ----
        LOAD_B256(1, b1);
        stage_half256(W, bn, K, kn, &Ws[o][0], 1, tid);
        stage_half256(A, bm, K, kn, &As[o][0], 1, tid);
        VMW(8);                          // guards A1(t) (issued 4 phases ago)
        BARX();
        MFMA16(acc01, b1);
        BARX();
        // ---- p2: Q(1,1) ----
        LOAD_A256(1);
        BARX();
        MFMA16(acc11, b1);
        BARX();
        // ---- p3: Q(1,0) ----
        VMW(4);                          // guards A0,B0(t+1) (issued 3 phases ago)
        BARX();
        MFMA16(acc10, b0);
        BARX();
    }
    // ---- last tile (no staging; drain 2 -> 0) ----
    {
        const int c = (nt - 1) & 1;
        const bf16_t* Ac = &As[c][0];
        const bf16_t* Wc = &Ws[c][0];
        LOAD_A256(0); LOAD_B256(0, b0);
        VMW(2);                          // guards B1(last)
        BARX();
        MFMA16(acc00, b0);
        BARX();
        LOAD_B256(1, b1);
        VMW(0);                          // guards A1(last)
        BARX();
        MFMA16(acc01, b1);
        BARX();
        LOAD_A256(1);
        BARX();
        MFMA16(acc11, b1);
        MFMA16(acc10, b0);
    }

    // Epilogue. C/D layout: col = lane&15, row = (lane>>4)*4 + reg
    const int fq = lane >> 4;
    #define EPILOG256(ACC, QR, QC)                                           \
        _Pragma("unroll")                                                    \
        for (int mi = 0; mi < 4; ++mi) {                                     \
          const int row0 = bm + (QR)*128 + vm*64 + mi*16 + fq*4;             \
          _Pragma("unroll")                                                  \
          for (int nj = 0; nj < 2; ++nj) {                                   \
            const int col = bn + (QC)*128 + vn*32 + nj*16 + fr;              \
            const float bcol = BIASROW ? 0.0f : bias[col];                   \
            _Pragma("unroll")                                                \
            for (int r = 0; r < 4; ++r) {                                    \
              float v = ACC[mi][nj][r] + (BIASROW ? bias[row0 + r] : bcol);  \
              if constexpr (EPI == 2) v = gelu_tanh(v);                      \
              if constexpr (BF16OUT)                                         \
                  Cb[(size_t)(row0 + r) * N + col] = (bf16_t)v;              \
              else                                                           \
                  Cf[(size_t)(row0 + r) * N + col] = v;                      \
            }                                                                \
          }                                                                  \
        }
    EPILOG256(acc00, 0, 0);
    EPILOG256(acc01, 0, 1);
    EPILOG256(acc11, 1, 1);
    EPILOG256(acc10, 1, 0);
    #undef EPILOG256
}

// ---------------------------------------------------------------------------
// Depthwise causal k=3 short filter on u_t (3D, M) channel-major bf16.
// ---------------------------------------------------------------------------
__global__ __launch_bounds__(256) void shortfilter_kernel(
    const bf16_t* __restrict__ ut, const float* __restrict__ sw,
    const float* __restrict__ sb, bf16_t* __restrict__ x0t,
    float* __restrict__ vin)
{
    const int d = blockIdx.x;             // 0..1023
    const int c0 = d, c1 = DD + d, c2 = 2 * DD + d;
    const float w0a = sw[c0*3+0], w0b = sw[c0*3+1], w0c = sw[c0*3+2], b0 = sb[c0];
    const float w1a = sw[c1*3+0], w1b = sw[c1*3+1], w1c = sw[c1*3+2], b1 = sb[c1];
    const float w2a = sw[c2*3+0], w2b = sw[c2*3+1], w2c = sw[c2*3+2], b2 = sb[c2];
    const bf16_t* r0 = ut + (size_t)c0 * MM;
    const bf16_t* r1 = ut + (size_t)c1 * MM;
    const bf16_t* r2 = ut + (size_t)c2 * MM;
    bf16_t* o0 = x0t + (size_t)d * MM;
    float*  o1 = vin + (size_t)d * MM;
    for (int m0 = threadIdx.x * 8; m0 < MM; m0 += 2048) {
        const int l0 = m0 & (LL - 1);
        const bf16x8 a0 = *(const bf16x8*)(r0 + m0);
        const bf16x8 a1 = *(const bf16x8*)(r1 + m0);
        const bf16x8 a2 = *(const bf16x8*)(r2 + m0);
        float u0[10], u1[10], u2[10];
        u0[0] = u0[1] = u1[0] = u1[1] = u2[0] = u2[1] = 0.0f;
        if (l0 != 0) {
            u0[0] = (float)r0[m0-2]; u0[1] = (float)r0[m0-1];
            u1[0] = (float)r1[m0-2]; u1[1] = (float)r1[m0-1];
            u2[0] = (float)r2[m0-2]; u2[1] = (float)r2[m0-1];
        }
        #pragma unroll
        for (int i = 0; i < 8; ++i) {
            u0[i+2] = (float)a0[i];
            u1[i+2] = (float)a1[i];
            u2[i+2] = (float)a2[i];
        }
        bf16x8 ov;
        float v1o[8];
        #pragma unroll
        for (int i = 0; i < 8; ++i) {
            const float v0 = w0c*u0[i+2] + w0b*u0[i+1] + w0a*u0[i] + b0;
            const float v1 = w1c*u1[i+2] + w1b*u1[i+1] + w1a*u1[i] + b1;
            const float v2 = w2c*u2[i+2] + w2b*u2[i+1] + w2a*u2[i] + b2;
            ov[i] = (bf16_t)v0;
            v1o[i] = v2 * v1;
        }
        *(bf16x8*)(o0 + m0) = ov;
        *(float4*)(o1 + m0)     = make_float4(v1o[0], v1o[1], v1o[2], v1o[3]);
        *(float4*)(o1 + m0 + 4) = make_float4(v1o[4], v1o[5], v1o[6], v1o[7]);
    }
}

// ---------------------------------------------------------------------------
// Implicit filter MLP, phase 1: h2t (64, L).
// ---------------------------------------------------------------------------
__global__ __launch_bounds__(256) void filtermlp_kernel(
    const float* __restrict__ w1, const float* __restrict__ b1,
    const float* __restrict__ f1, const float* __restrict__ w2,
    const float* __restrict__ b2, const float* __restrict__ f2,
    float* __restrict__ h2t)
{
    __shared__ float w2s[64 * 64];      // 16 KB
    __shared__ float h1s[64][32];       // 8 KB, [j][l]
    const int tid = threadIdx.x;
    #pragma unroll
    for (int i = 0; i < 4; ++i)
        ((float4*)w2s)[tid + 256 * i] = ((const float4*)w2)[tid + 256 * i];

    const int l0 = blockIdx.x * 32;
    const int l  = tid & 31;
    const float fl = (float)(l0 + l);
    const float t   = fl * (1.0f / (float)(LL - 1));
    const float ang = 1e-4f * 6.283185307179586f * fl * (1.0f / (float)LL);
    const float z0 = t, z1 = cosf(ang), z2 = -sinf(ang);

    #pragma unroll
    for (int i = 0; i < 8; ++i) {
        const int j = (tid >> 5) + 8 * i;
        const float s = w1[j*3+0]*z0 + w1[j*3+1]*z1 + w1[j*3+2]*z2 + b1[j];
        h1s[j][l] = sinf(f1[j] * s);
    }
    __syncthreads();

    const int jb = (tid >> 5) * 8;
    float acc[8];
    #pragma unroll
    for (int i = 0; i < 8; ++i) acc[i] = b2[jb + i];
    #pragma unroll
    for (int jj = 0; jj < 64; jj += 4) {
        const float h0 = h1s[jj + 0][l];
        const float h1v = h1s[jj + 1][l];
        const float h2v = h1s[jj + 2][l];
        const float h3 = h1s[jj + 3][l];
        #pragma unroll
        for (int i = 0; i < 8; ++i) {
            const float4 wv = *(const float4*)&w2s[(jb + i) * 64 + jj];
            acc[i] += wv.x * h0 + wv.y * h1v + wv.z * h2v + wv.w * h3;
        }
    }
    #pragma unroll
    for (int i = 0; i < 8; ++i)
        h2t[(size_t)(jb + i) * LL + l0 + l] = sinf(f2[jb + i] * acc[i]);
}

// ---------------------------------------------------------------------------
// Implicit filter, phase 2: kfilt[d][l] = (w3[d,:] . h2t[:,l]) * exp(-t|delta_d|)
// ---------------------------------------------------------------------------
__global__ __launch_bounds__(256) void filtermod_kernel(
    const float* __restrict__ w3, const float* __restrict__ h2t,
    float* __restrict__ kfilt)
{
    __shared__ float w3s[32 * 64];      // 8 KB
    const int d0 = blockIdx.y * 32;
    const int l  = blockIdx.x * 256 + threadIdx.x;
    for (int i = threadIdx.x; i < 32 * 64; i += 256) w3s[i] = w3[d0 * 64 + i];
    __syncthreads();
    float acc[32] = {};
    for (int j = 0; j < 64; ++j) {
        const float v = h2t[j * LL + l];
        #pragma unroll
        for (int dd = 0; dd < 32; ++dd) acc[dd] += w3s[dd*64 + j] * v;
    }
    const float t = (float)l / (float)(LL - 1);
    const float min_decay = -3.0701134573253944f;   // ln(1e-2)/1.5
    const float max_decay = -15.350567286626972f;   // ln(1e-2)/0.3
    #pragma unroll
    for (int dd = 0; dd < 32; ++dd) {
        const int d = d0 + dd;
        const float delta = fabsf(min_decay + (max_decay - min_decay) * (float)d / (float)(DD - 1));
        kfilt[(size_t)d * LL + l] = acc[dd] * expf(-t * delta);
    }
}

// ---------------------------------------------------------------------------
// 4096-point complex Stockham RADIX-8 FFT, in-place in 32 KB LDS.
// ---------------------------------------------------------------------------
template<int SIGN>
__device__ __forceinline__ void fft4096_r8_ip(float2* __restrict__ buf)
{
    const float fs = (float)SIGN;
    const float RH = 0.7071067811865476f;   // sqrt(2)/2
    const int tid = threadIdx.x;            // 0..511
    #pragma unroll
    for (int t = 0; t < 4; ++t) {
        const int ls = 3 * t;               // log2(stride): 0,3,6,9
        const int s  = 1 << ls;
        const float theta = fs * 6.283185307179586f / (float)(4096 >> ls);
        float2 a[8];
        #pragma unroll
        for (int m = 0; m < 8; ++m) a[m] = buf[SWZ(tid + m * 512)];
        __syncthreads();
        const int p = tid >> ls;
        const int q = tid & (s - 1);
        float sn, cs;
        __sincosf(theta * (float)p, &sn, &cs);
        const float2 W1 = make_float2(cs, sn);
        const float2 W2 = cmul(W1, W1);
        const float2 W3 = cmul(W2, W1);
        const float2 W4 = cmul(W2, W2);
        const float2 W5 = cmul(W4, W1);
        const float2 W6 = cmul(W4, W2);
        const float2 W7 = cmul(W4, W3);
        const float2 es = cadd(a[0], a[4]), ed = csub(a[0], a[4]);
        const float2 fs2 = cadd(a[2], a[6]), fd = csub(a[2], a[6]);
        const float2 E0 = cadd(es, fs2);
        const float2 E1 = cadd(ed, cmuli(fd, fs));
        const float2 E2 = csub(es, fs2);
        const float2 E3 = csub(ed, cmuli(fd, fs));
        const float2 os = cadd(a[1], a[5]), od = csub(a[1], a[5]);
        const float2 gs = cadd(a[3], a[7]), gd = csub(a[3], a[7]);
        const float2 O0 = cadd(os, gs);
        const float2 O1 = cadd(od, cmuli(gd, fs));
        const float2 O2 = csub(os, gs);
        const float2 O3 = csub(od, cmuli(gd, fs));
        const float2 T0 = O0;
        const float2 T1 = make_float2(RH * (O1.x - fs * O1.y), RH * (fs * O1.x + O1.y));
        const float2 T2 = cmuli(O2, fs);
        const float2 T3 = make_float2(RH * (-O3.x - fs * O3.y), RH * (fs * O3.x - O3.y));
        const int o = q + (p << (ls + 3));
        buf[SWZ(o)]         = cadd(E0, T0);
        buf[SWZ(o + s)]     = cmul(W1, cadd(E1, T1));
        buf[SWZ(o + 2*s)]   = cmul(W2, cadd(E2, T2));
        buf[SWZ(o + 3*s)]   = cmul(W3, cadd(E3, T3));
        buf[SWZ(o + 4*s)]   = cmul(W4, csub(E0, T0));
        buf[SWZ(o + 5*s)]   = cmul(W5, csub(E1, T1));
        buf[SWZ(o + 6*s)]   = cmul(W6, csub(E2, T2));
        buf[SWZ(o + 7*s)]   = cmul(W7, csub(E3, T3));
        __syncthreads();
    }
}

// ---------------------------------------------------------------------------
// FFT of filter rows, two real rows per block.
// ---------------------------------------------------------------------------
__global__ __launch_bounds__(512, 4) void kfft_kernel(
    const float* __restrict__ kfilt, float2* __restrict__ Kf)
{
    __shared__ float2 fb[4096];           // 32 KB
    const int d0 = blockIdx.x * 2;
    const float* k0 = kfilt + (size_t)d0 * LL;
    const float* k1 = k0 + LL;
    const float inv = 1.0f / 4096.0f;
    const int tid = threadIdx.x;
    for (int i = tid; i < 2048; i += 512) {
        fb[SWZ(i)]        = make_float2(k0[i] * inv, k1[i] * inv);
        fb[SWZ(i + 2048)] = make_float2(0.f, 0.f);
    }
    __syncthreads();
    fft4096_r8_ip<-1>(fb);
    float2* o0 = Kf + (size_t)d0 * KF_STRIDE;
    float2* o1 = o0 + KF_STRIDE;
    for (int k = tid; k <= 2048; k += 512) {
        const float2 z1 = fb[SWZ(k)];
        const float2 z2 = fb[SWZ((4096 - k) & 4095)];
        o0[k] = make_float2(0.5f * (z1.x + z2.x), 0.5f * (z1.y - z2.y));
        o1[k] = make_float2(0.5f * (z1.y + z2.y), 0.5f * (z2.x - z1.x));
    }
}

// ---------------------------------------------------------------------------
// Long conv, two real rows per block: z = v1 + i*v2, filter k is REAL.
// ---------------------------------------------------------------------------
__global__ __launch_bounds__(512, 4) void fftconv_kernel(
    float* __restrict__ vio, const float2* __restrict__ Kf,
    const float* __restrict__ fbias)
{
    __shared__ float2 fb[4096];           // 32 KB
    const int blk = blockIdx.x;          // [0, 2048)
    const int d   = blk >> 1;
    float* v1 = vio + (size_t)(2 * blk) * LL;
    float* v2 = v1 + LL;
    const int tid = threadIdx.x;
    for (int i = tid; i < 2048; i += 512) {
        fb[SWZ(i)]        = make_float2(v1[i], v2[i]);
        fb[SWZ(i + 2048)] = make_float2(0.f, 0.f);
    }
    __syncthreads();
    fft4096_r8_ip<-1>(fb);
    const float2* kf = Kf + (size_t)d * KF_STRIDE;
    for (int i = tid; i < 4096; i += 512) {
        float2 k;
        if (i <= 2048) k = kf[i];
        else { const float2 t = kf[4096 - i]; k = make_float2(t.x, -t.y); }
        fb[SWZ(i)] = cmul(fb[SWZ(i)], k);
    }
    __syncthreads();
    fft4096_r8_ip<1>(fb);
    const float bias = fbias[d];
    for (int i = tid; i < 2048; i += 512) {
        const float2 zy = fb[SWZ(i)];
        v1[i] = zy.x + bias * v1[i];
        v2[i] = zy.y + bias * v2[i];
    }
}

// ---------------------------------------------------------------------------
// gated_bf16(B,L,D) = bf16( y(D,B,L) * x0t(D,B,L) )  -- LDS 32x32 transpose
// ---------------------------------------------------------------------------
__global__ __launch_bounds__(256) void gate_transpose_kernel(
    const float* __restrict__ y, const bf16_t* __restrict__ x0t,
    bf16_t* __restrict__ g)
{
    __shared__ float tile[32][33];
    const int b  = blockIdx.z;
    const int l0 = blockIdx.x * 32;
    const int d0 = blockIdx.y * 32;
    const int tx  = threadIdx.x & 31;
    const int tyb = threadIdx.x >> 5;    // 0..7
    #pragma unroll
    for (int i = 0; i < 4; ++i) {
        const int dy = tyb + i * 8;
        const size_t src = ((size_t)(d0 + dy) * BB + b) * LL + l0 + tx;
        tile[dy][tx] = y[src] * (float)x0t[src];
    }
    __syncthreads();
    #pragma unroll
    for (int i = 0; i < 4; ++i) {
        const int ly = tyb + i * 8;
        g[((size_t)(b * LL + l0 + ly)) * DD + d0 + tx] = (bf16_t)tile[tx][ly];
    }
}

// ---------------------------------------------------------------------------
// Launch
// ---------------------------------------------------------------------------
extern "C" void kernel_launch(void* const* d_in, const int* in_sizes, int n_in,
                              void* d_out, int out_size, void* d_ws, size_t ws_size,
                              hipStream_t stream)
{
    (void)in_sizes; (void)n_in; (void)out_size; (void)ws_size;
    const float* x   = (const float*)d_in[0];
    const float* nw0 = (const float*)d_in[1];
    const float* ipw = (const float*)d_in[2];
    const float* ipb = (const float*)d_in[3];
    const float* sfw = (const float*)d_in[4];
    const float* sfb = (const float*)d_in[5];
    const float* w1  = (const float*)d_in[6];
    const float* b1  = (const float*)d_in[7];
    const float* f1  = (const float*)d_in[8];
    const float* w2  = (const float*)d_in[9];
    const float* b2  = (const float*)d_in[10];
    const float* f2  = (const float*)d_in[11];
    const float* w3  = (const float*)d_in[12];
    const float* fbv = (const float*)d_in[13];
    const float* opw = (const float*)d_in[14];
    const float* opb = (const float*)d_in[15];
    const float* nw1 = (const float*)d_in[16];
    const float* fw1 = (const float*)d_in[17];
    const float* fb1 = (const float*)d_in[18];
    const float* fw2 = (const float*)d_in[19];
    const float* fb2 = (const float*)d_in[20];
    float* out = (float*)d_out;

    float* ws = (float*)d_ws;
    bf16_t* utb    = (bf16_t*)ws;
    bf16_t* gatedb = (bf16_t*)ws;                       // 8,388,608 bf16
    float*  h      = ws + 4194304;                      // 8,388,608 f
    bf16_t* midb   = (bf16_t*)(ws + 12582912);          // 16,777,216 bf16
    bf16_t* xnb    = (bf16_t*)(ws + 25165824);          // 8M bf16 (also hn later)
    bf16_t* x0tb   = (bf16_t*)(ws + 29360128);          // 8,388,608 bf16 (D,B,L)
    float*  vio    = ws + 37748736;                     // 8,388,608 f (D,B,L)
    float*  kfilt  = ws + 46137344;                     // 2,097,152 f
    float2* Kf     = (float2*)(ws + 48234496);          // 1024 x KF_STRIDE cplx
    bf16_t* ipwb   = (bf16_t*)(ws + 52445184);          // 3,145,728 bf16
    bf16_t* opwb   = ipwb + 3145728;                    // 1,048,576 bf16
    bf16_t* fw1b   = opwb + 1048576;                    // 2,097,152 bf16
    bf16_t* fw2b   = fw1b + 2097152;                    // 2,097,152 bf16
    float*  h2t    = ws + 56639488;                     // (64, L) = 131,072 f

    // 0. weight casts (single launch, region-dispatched)
    cast_all_kernel<<<8192, 256, 0, stream>>>(ipw, opw, fw1, fw2,
                                              ipwb, opwb, fw1b, fw2b);
    // 1. implicit filter: MLP phase (h2t), modulation phase (kfilt), FFT (Kf)
    filtermlp_kernel<<<LL/32, 256, 0, stream>>>(w1, b1, f1, w2, b2, f2, h2t);
    filtermod_kernel<<<dim3(LL/256, DD/32), 256, 0, stream>>>(w3, h2t, kfilt);
    kfft_kernel<<<DD/2, 512, 0, stream>>>(kfilt, Kf);
    // 2. xn = bf16(rmsnorm(x, norm_in_w))
    rmsnorm_bf16_kernel<<<MM, 256, 0, stream>>>(x, nw0, xnb);
    // 3. u_t = in_proj_w @ xn^T + b (transposed output, bf16) -- 256^2 8-phase
    gemm256_kernel<0, true, true><<<dim3(MM/256, 3072/256), 512, 0, stream>>>(
        ipwb, xnb, ipb, nullptr, utb, 3*DD, MM, DD);
    // 4. short filter -> x0t (D,B,L) bf16, vin (D,B,L) fp32
    shortfilter_kernel<<<DD, 256, 0, stream>>>(utb, sfw, sfb, x0tb, vio);
    // 5. vio <- causal_conv(vio, k) + filter_bias * vio   (2 rows per block)
    fftconv_kernel<<<BB*DD/2, 512, 0, stream>>>(vio, Kf, fbv);
    // 6. gated_bf16(B,L,D) = y * x0
    gate_transpose_kernel<<<dim3(LL/32, DD/32, BB), 256, 0, stream>>>(vio, x0tb, gatedb);
    // 7. h = gated @ out_proj_w^T + b + x   (M=8192, N=1024, K=1024)
    gemm_mfma_kernel<1, false><<<dim3(DD/128, MM/128), 256, 0, stream>>>(
        gatedb, opwb, opb, x, h, nullptr, MM, DD, DD);
    // 8. hn = bf16(rmsnorm(h, norm_w))
    rmsnorm_bf16_kernel<<<MM, 256, 0, stream>>>(h, nw1, xnb);
    // 9. mid = bf16(gelu(hn @ ffn_w1^T + b))  (M=8192, N=2048, K=1024) -- 256^2
    gemm256_kernel<2, true><<<dim3(2*DD/256, MM/256), 512, 0, stream>>>(
        xnb, fw1b, fb1, nullptr, midb, MM, 2*DD, DD);
    // 10. out = mid @ ffn_w2^T + b + h      (M=8192, N=1024, K=2048)
    gemm_mfma_kernel<1, false><<<dim3(DD/128, MM/128), 256, 0, stream>>>(
        midb, fw2b, fb2, h, out, nullptr, MM, DD, 2*DD);
}

// Round 5
// 540.050 us; speedup vs baseline: 1.1488x; 1.1488x over previous
//
#include <hip/hip_runtime.h>
#include <hip/hip_bf16.h>
#include <cstddef>

// ---------------------------------------------------------------------------
// Constants for this problem: B=4, L=2048, D=1024
// ---------------------------------------------------------------------------
#define BB 4
#define LL 2048
#define DD 1024
#define MM (BB*LL)          // 8192 tokens
#define KF_STRIDE 2056      // complex elements per Kf row (>= 2049, 16B-aligned)

// LDS bank swizzle for float2 arrays: spreads Stockham write streams across
// bank-pairs. Modifies bits 2-3 only (stays in range).
#define SWZ(a) ((a) ^ (((a) >> 4) & 12))

typedef __bf16 bf16_t;
typedef __attribute__((ext_vector_type(8))) __bf16 bf16x8;
typedef __attribute__((ext_vector_type(4))) __bf16 bf16x4;
typedef __attribute__((ext_vector_type(4))) float f32x4;

// async global->LDS, 16 bytes per lane (global_load_lds_dwordx4)
#define GLD_LDS16(gp, lp) __builtin_amdgcn_global_load_lds(                 \
    (const __attribute__((address_space(1))) unsigned int*)(gp),            \
    (__attribute__((address_space(3))) unsigned int*)(lp), 16, 0, 0)

__device__ __forceinline__ float gelu_tanh(float x) {
    const float c = 0.7978845608028654f;   // sqrt(2/pi)
    float t = tanhf(c * (x + 0.044715f * x * x * x));
    return 0.5f * x * (1.0f + t);
}

__device__ __forceinline__ float2 cmul(float2 a, float2 b) {
    return make_float2(a.x * b.x - a.y * b.y, a.x * b.y + a.y * b.x);
}
__device__ __forceinline__ float2 cadd(float2 a, float2 b) {
    return make_float2(a.x + b.x, a.y + b.y);
}
__device__ __forceinline__ float2 csub(float2 a, float2 b) {
    return make_float2(a.x - b.x, a.y - b.y);
}
// multiply by i*sigma (sigma = +-1)
__device__ __forceinline__ float2 cmuli(float2 z, float s) {
    return make_float2(-s * z.y, s * z.x);
}

// ---------------------------------------------------------------------------
// fp32 -> bf16 cast of all 4 weight matrices in ONE launch.
// ---------------------------------------------------------------------------
__global__ __launch_bounds__(256) void cast_all_kernel(
    const float* __restrict__ s0, const float* __restrict__ s1,
    const float* __restrict__ s2, const float* __restrict__ s3,
    bf16_t* __restrict__ d0, bf16_t* __restrict__ d1,
    bf16_t* __restrict__ d2, bf16_t* __restrict__ d3)
{
    const int b = blockIdx.x;
    const float* s; bf16_t* d; int base;
    if (b < 3072)      { s = s0; d = d0; base = b; }
    else if (b < 4096) { s = s1; d = d1; base = b - 3072; }
    else if (b < 6144) { s = s2; d = d2; base = b - 4096; }
    else               { s = s3; d = d3; base = b - 6144; }
    const int i = (base * 256 + threadIdx.x) * 4;
    const float4 v = *(const float4*)(s + i);
    bf16x4 o;
    o[0] = (bf16_t)v.x; o[1] = (bf16_t)v.y; o[2] = (bf16_t)v.z; o[3] = (bf16_t)v.w;
    *(bf16x4*)(d + i) = o;
}

// ---------------------------------------------------------------------------
// RMSNorm -> bf16 output: one block per row of 1024 floats
// ---------------------------------------------------------------------------
__global__ __launch_bounds__(256) void rmsnorm_bf16_kernel(
    const float* __restrict__ in, const float* __restrict__ w,
    bf16_t* __restrict__ out)
{
    const int row = blockIdx.x;
    const float4* ip = (const float4*)(in + (size_t)row * DD);
    float4 v = ip[threadIdx.x];
    float ss = v.x*v.x + v.y*v.y + v.z*v.z + v.w*v.w;
    #pragma unroll
    for (int off = 32; off > 0; off >>= 1) ss += __shfl_down(ss, off, 64);
    __shared__ float sums[4];
    const int wid = threadIdx.x >> 6;
    if ((threadIdx.x & 63) == 0) sums[wid] = ss;
    __syncthreads();
    const float tot = sums[0] + sums[1] + sums[2] + sums[3];
    const float scale = rsqrtf(tot * (1.0f / (float)DD) + 1e-8f);
    const float4 wv = ((const float4*)w)[threadIdx.x];
    bf16x4 o;
    o[0] = (bf16_t)(v.x * scale * wv.x);
    o[1] = (bf16_t)(v.y * scale * wv.y);
    o[2] = (bf16_t)(v.z * scale * wv.z);
    o[3] = (bf16_t)(v.w * scale * wv.w);
    *(bf16x4*)(out + (size_t)row * DD + threadIdx.x * 4) = o;
}

// ---------------------------------------------------------------------------
// bf16 MFMA GEMM: C(M,N) = epi(A(M,K) @ W(N,K)^T + bias) [+ res]
// 128x128 tile, BK=64, 256 thr (4 waves, 2x2), each wave 4x4 16x16x32 tiles.
// R10 schedule (VERIFIED 481.5us total): double-buffered 2-phase -- issue
// next-tile global_load_lds into buf^1 first, compute cur tile, ONE
// __syncthreads() per K-tile. s_setprio(1) around MFMA clusters.
// R13: 8-phase 256^2 port REVERTED (two strikes: MfmaUtil 26% -> 10%;
// vmcnt slack < HBM latency at 2 waves/SIMD, loads not L2-resident).
// NEW in R13: bijective XCD-chunk swizzle (T1) -- all our grids have
// nwg%8==0; consecutive blocks on one XCD now share the A panel and walk
// W sequentially, cutting cross-XCD L2 duplication (FETCH 49MB vs 20MB
// unique on step 3).
// LDS chunk swizzle: 16-B chunk (row, q) stored at chunk pos row*8+(q^(row&7));
// staging pre-swizzles the GLOBAL source; fragment ds_reads apply the same
// XOR -> bank-conflict-free (0 measured).
// EPI: 0 = bias, 1 = bias + residual, 2 = bias + tanh-GELU
// BIASROW: bias indexed by output row (for transposed-output GEMMs)
// ---------------------------------------------------------------------------
template<int EPI, bool BF16OUT, bool BIASROW = false>
__global__ __launch_bounds__(256) void gemm_mfma_kernel(
    const bf16_t* __restrict__ A,    // (M,K)
    const bf16_t* __restrict__ W,    // (N,K)
    const float* __restrict__ bias,  // (N) or (M) if BIASROW
    const float* __restrict__ res,   // (M,N) or nullptr
    float* __restrict__ Cf,          // fp32 out (if !BF16OUT)
    bf16_t* __restrict__ Cb,         // bf16 out (if BF16OUT)
    int M, int N, int K)
{
    __shared__ __align__(16) bf16_t As[2][128 * 64];   // 32 KB
    __shared__ __align__(16) bf16_t Ws[2][128 * 64];   // 32 KB
    const int tid  = threadIdx.x;

    // T1: bijective XCD-chunk swizzle (requires nwg % 8 == 0 -- true for all
    // four GEMM launches: 1536 / 512 / 1024 / 512 blocks).
    const int nwgx = gridDim.x;
    const int nwg  = nwgx * gridDim.y;
    const int bidl = blockIdx.y * nwgx + blockIdx.x;
    const int swz  = (bidl & 7) * (nwg >> 3) + (bidl >> 3);
    const int bm   = (swz / nwgx) * 128;
    const int bn   = (swz % nwgx) * 128;

    const int lane = tid & 63;
    const int wave = tid >> 6;
    const int wr   = (wave >> 1) * 64;
    const int wc   = (wave & 1) * 64;

    int srow[4], sqg[4];
    #pragma unroll
    for (int c = 0; c < 4; ++c) {
        const int p = c * 256 + tid;
        srow[c] = p >> 3;
        sqg[c]  = (((p & 7) ^ (srow[c] & 7)) << 3);
    }

    f32x4 acc[4][4] = {};

    const int fr = lane & 15;
    const int fc = (lane >> 4) * 8;

    const int nt = K >> 6;

    #pragma unroll
    for (int c = 0; c < 4; ++c) {
        GLD_LDS16(A + (size_t)(bm + srow[c]) * K + sqg[c],
                  &As[0][c * 2048 + tid * 8]);
        GLD_LDS16(W + (size_t)(bn + srow[c]) * K + sqg[c],
                  &Ws[0][c * 2048 + tid * 8]);
    }
    __syncthreads();

    int cur = 0;
    for (int t = 0; t < nt; ++t) {
        if (t + 1 < nt) {
            const int k0 = (t + 1) << 6;
            #pragma unroll
            for (int c = 0; c < 4; ++c) {
                GLD_LDS16(A + (size_t)(bm + srow[c]) * K + k0 + sqg[c],
                          &As[cur ^ 1][c * 2048 + tid * 8]);
                GLD_LDS16(W + (size_t)(bn + srow[c]) * K + k0 + sqg[c],
                          &Ws[cur ^ 1][c * 2048 + tid * 8]);
            }
        }
        #pragma unroll
        for (int ks = 0; ks < 64; ks += 32) {
            const int q = (ks + fc) >> 3;
            bf16x8 af[4], wf[4];
            #pragma unroll
            for (int i = 0; i < 4; ++i) {
                const int r = wr + i*16 + fr;
                af[i] = *(const bf16x8*)(&As[cur][r * 64 + ((q ^ (r & 7)) << 3)]);
            }
            #pragma unroll
            for (int j = 0; j < 4; ++j) {
                const int r = wc + j*16 + fr;
                wf[j] = *(const bf16x8*)(&Ws[cur][r * 64 + ((q ^ (r & 7)) << 3)]);
            }
            __builtin_amdgcn_s_setprio(1);
            #pragma unroll
            for (int i = 0; i < 4; ++i)
                #pragma unroll
                for (int j = 0; j < 4; ++j)
                    acc[i][j] = __builtin_amdgcn_mfma_f32_16x16x32_bf16(
                        af[i], wf[j], acc[i][j], 0, 0, 0);
            __builtin_amdgcn_s_setprio(0);
        }
        __syncthreads();
        cur ^= 1;
    }

    const int fq = lane >> 4;
    #pragma unroll
    for (int i = 0; i < 4; ++i) {
        const int row0 = bm + wr + i*16 + fq*4;
        #pragma unroll
        for (int j = 0; j < 4; ++j) {
            const int col = bn + wc + j*16 + fr;
            const float bcol = BIASROW ? 0.0f : bias[col];
            #pragma unroll
            for (int r = 0; r < 4; ++r) {
                float v = acc[i][j][r] + (BIASROW ? bias[row0 + r] : bcol);
                if constexpr (EPI == 2) v = gelu_tanh(v);
                if constexpr (EPI == 1) v += res[(size_t)(row0 + r) * N + col];
                if constexpr (BF16OUT)
                    Cb[(size_t)(row0 + r) * N + col] = (bf16_t)v;
                else
                    Cf[(size_t)(row0 + r) * N + col] = v;
            }
        }
    }
}

// ---------------------------------------------------------------------------
// Depthwise causal k=3 short filter on u_t (3D, M) channel-major bf16.
// Vectorized bf16x8 loads (16 B/lane), 8 positions per thread, 16-B stores.
// ---------------------------------------------------------------------------
__global__ __launch_bounds__(256) void shortfilter_kernel(
    const bf16_t* __restrict__ ut, const float* __restrict__ sw,
    const float* __restrict__ sb, bf16_t* __restrict__ x0t,
    float* __restrict__ vin)
{
    const int d = blockIdx.x;             // 0..1023
    const int c0 = d, c1 = DD + d, c2 = 2 * DD + d;
    const float w0a = sw[c0*3+0], w0b = sw[c0*3+1], w0c = sw[c0*3+2], b0 = sb[c0];
    const float w1a = sw[c1*3+0], w1b = sw[c1*3+1], w1c = sw[c1*3+2], b1 = sb[c1];
    const float w2a = sw[c2*3+0], w2b = sw[c2*3+1], w2c = sw[c2*3+2], b2 = sb[c2];
    const bf16_t* r0 = ut + (size_t)c0 * MM;
    const bf16_t* r1 = ut + (size_t)c1 * MM;
    const bf16_t* r2 = ut + (size_t)c2 * MM;
    bf16_t* o0 = x0t + (size_t)d * MM;
    float*  o1 = vin + (size_t)d * MM;
    for (int m0 = threadIdx.x * 8; m0 < MM; m0 += 2048) {
        const int l0 = m0 & (LL - 1);
        const bf16x8 a0 = *(const bf16x8*)(r0 + m0);
        const bf16x8 a1 = *(const bf16x8*)(r1 + m0);
        const bf16x8 a2 = *(const bf16x8*)(r2 + m0);
        float u0[10], u1[10], u2[10];
        u0[0] = u0[1] = u1[0] = u1[1] = u2[0] = u2[1] = 0.0f;
        if (l0 != 0) {
            u0[0] = (float)r0[m0-2]; u0[1] = (float)r0[m0-1];
            u1[0] = (float)r1[m0-2]; u1[1] = (float)r1[m0-1];
            u2[0] = (float)r2[m0-2]; u2[1] = (float)r2[m0-1];
        }
        #pragma unroll
        for (int i = 0; i < 8; ++i) {
            u0[i+2] = (float)a0[i];
            u1[i+2] = (float)a1[i];
            u2[i+2] = (float)a2[i];
        }
        bf16x8 ov;
        float v1o[8];
        #pragma unroll
        for (int i = 0; i < 8; ++i) {
            const float v0 = w0c*u0[i+2] + w0b*u0[i+1] + w0a*u0[i] + b0;
            const float v1 = w1c*u1[i+2] + w1b*u1[i+1] + w1a*u1[i] + b1;
            const float v2 = w2c*u2[i+2] + w2b*u2[i+1] + w2a*u2[i] + b2;
            ov[i] = (bf16_t)v0;
            v1o[i] = v2 * v1;
        }
        *(bf16x8*)(o0 + m0) = ov;
        *(float4*)(o1 + m0)     = make_float4(v1o[0], v1o[1], v1o[2], v1o[3]);
        *(float4*)(o1 + m0 + 4) = make_float4(v1o[4], v1o[5], v1o[6], v1o[7]);
    }
}

// ---------------------------------------------------------------------------
// Implicit filter MLP, phase 1: h2t (64, L).
// Block = 32 l-positions x 64 j, grid = 64 blocks.
// ---------------------------------------------------------------------------
__global__ __launch_bounds__(256) void filtermlp_kernel(
    const float* __restrict__ w1, const float* __restrict__ b1,
    const float* __restrict__ f1, const float* __restrict__ w2,
    const float* __restrict__ b2, const float* __restrict__ f2,
    float* __restrict__ h2t)
{
    __shared__ float w2s[64 * 64];      // 16 KB
    __shared__ float h1s[64][32];       // 8 KB, [j][l]
    const int tid = threadIdx.x;
    #pragma unroll
    for (int i = 0; i < 4; ++i)
        ((float4*)w2s)[tid + 256 * i] = ((const float4*)w2)[tid + 256 * i];

    const int l0 = blockIdx.x * 32;
    const int l  = tid & 31;
    const float fl = (float)(l0 + l);
    const float t   = fl * (1.0f / (float)(LL - 1));
    const float ang = 1e-4f * 6.283185307179586f * fl * (1.0f / (float)LL);
    const float z0 = t, z1 = cosf(ang), z2 = -sinf(ang);

    #pragma unroll
    for (int i = 0; i < 8; ++i) {
        const int j = (tid >> 5) + 8 * i;
        const float s = w1[j*3+0]*z0 + w1[j*3+1]*z1 + w1[j*3+2]*z2 + b1[j];
        h1s[j][l] = sinf(f1[j] * s);
    }
    __syncthreads();

    const int jb = (tid >> 5) * 8;
    float acc[8];
    #pragma unroll
    for (int i = 0; i < 8; ++i) acc[i] = b2[jb + i];
    #pragma unroll
    for (int jj = 0; jj < 64; jj += 4) {
        const float h0 = h1s[jj + 0][l];
        const float h1v = h1s[jj + 1][l];
        const float h2v = h1s[jj + 2][l];
        const float h3 = h1s[jj + 3][l];
        #pragma unroll
        for (int i = 0; i < 8; ++i) {
            const float4 wv = *(const float4*)&w2s[(jb + i) * 64 + jj];
            acc[i] += wv.x * h0 + wv.y * h1v + wv.z * h2v + wv.w * h3;
        }
    }
    #pragma unroll
    for (int i = 0; i < 8; ++i)
        h2t[(size_t)(jb + i) * LL + l0 + l] = sinf(f2[jb + i] * acc[i]);
}

// ---------------------------------------------------------------------------
// Implicit filter, phase 2: kfilt[d][l] = (w3[d,:] . h2t[:,l]) * exp(-t|delta_d|)
// ---------------------------------------------------------------------------
__global__ __launch_bounds__(256) void filtermod_kernel(
    const float* __restrict__ w3, const float* __restrict__ h2t,
    float* __restrict__ kfilt)
{
    __shared__ float w3s[32 * 64];      // 8 KB
    const int d0 = blockIdx.y * 32;
    const int l  = blockIdx.x * 256 + threadIdx.x;
    for (int i = threadIdx.x; i < 32 * 64; i += 256) w3s[i] = w3[d0 * 64 + i];
    __syncthreads();
    float acc[32] = {};
    for (int j = 0; j < 64; ++j) {
        const float v = h2t[j * LL + l];
        #pragma unroll
        for (int dd = 0; dd < 32; ++dd) acc[dd] += w3s[dd*64 + j] * v;
    }
    const float t = (float)l / (float)(LL - 1);
    const float min_decay = -3.0701134573253944f;   // ln(1e-2)/1.5
    const float max_decay = -15.350567286626972f;   // ln(1e-2)/0.3
    #pragma unroll
    for (int dd = 0; dd < 32; ++dd) {
        const int d = d0 + dd;
        const float delta = fabsf(min_decay + (max_decay - min_decay) * (float)d / (float)(DD - 1));
        kfilt[(size_t)d * LL + l] = acc[dd] * expf(-t * delta);
    }
}

// ---------------------------------------------------------------------------
// 4096-point complex Stockham RADIX-8 FFT, in-place in 32 KB LDS.
// 4 stages (4096 = 8^4), 512 threads, one 8-point butterfly per thread per
// stage (read-all / barrier / write-all: race-free).
// SIGN = -1 forward, +1 unnormalized inverse. Ends with __syncthreads().
// ---------------------------------------------------------------------------
template<int SIGN>
__device__ __forceinline__ void fft4096_r8_ip(float2* __restrict__ buf)
{
    const float fs = (float)SIGN;
    const float RH = 0.7071067811865476f;   // sqrt(2)/2
    const int tid = threadIdx.x;            // 0..511
    #pragma unroll
    for (int t = 0; t < 4; ++t) {
        const int ls = 3 * t;               // log2(stride): 0,3,6,9
        const int s  = 1 << ls;
        const float theta = fs * 6.283185307179586f / (float)(4096 >> ls);
        float2 a[8];
        #pragma unroll
        for (int m = 0; m < 8; ++m) a[m] = buf[SWZ(tid + m * 512)];
        __syncthreads();
        const int p = tid >> ls;
        const int q = tid & (s - 1);
        float sn, cs;
        __sincosf(theta * (float)p, &sn, &cs);
        const float2 W1 = make_float2(cs, sn);
        const float2 W2 = cmul(W1, W1);
        const float2 W3 = cmul(W2, W1);
        const float2 W4 = cmul(W2, W2);
        const float2 W5 = cmul(W4, W1);
        const float2 W6 = cmul(W4, W2);
        const float2 W7 = cmul(W4, W3);
        const float2 es = cadd(a[0], a[4]), ed = csub(a[0], a[4]);
        const float2 fs2 = cadd(a[2], a[6]), fd = csub(a[2], a[6]);
        const float2 E0 = cadd(es, fs2);
        const float2 E1 = cadd(ed, cmuli(fd, fs));
        const float2 E2 = csub(es, fs2);
        const float2 E3 = csub(ed, cmuli(fd, fs));
        const float2 os = cadd(a[1], a[5]), od = csub(a[1], a[5]);
        const float2 gs = cadd(a[3], a[7]), gd = csub(a[3], a[7]);
        const float2 O0 = cadd(os, gs);
        const float2 O1 = cadd(od, cmuli(gd, fs));
        const float2 O2 = csub(os, gs);
        const float2 O3 = csub(od, cmuli(gd, fs));
        const float2 T0 = O0;
        const float2 T1 = make_float2(RH * (O1.x - fs * O1.y), RH * (fs * O1.x + O1.y));
        const float2 T2 = cmuli(O2, fs);
        const float2 T3 = make_float2(RH * (-O3.x - fs * O3.y), RH * (fs * O3.x - O3.y));
        const int o = q + (p << (ls + 3));
        buf[SWZ(o)]         = cadd(E0, T0);
        buf[SWZ(o + s)]     = cmul(W1, cadd(E1, T1));
        buf[SWZ(o + 2*s)]   = cmul(W2, cadd(E2, T2));
        buf[SWZ(o + 3*s)]   = cmul(W3, cadd(E3, T3));
        buf[SWZ(o + 4*s)]   = cmul(W4, csub(E0, T0));
        buf[SWZ(o + 5*s)]   = cmul(W5, csub(E1, T1));
        buf[SWZ(o + 6*s)]   = cmul(W6, csub(E2, T2));
        buf[SWZ(o + 7*s)]   = cmul(W7, csub(E3, T3));
        __syncthreads();
    }
}

// ---------------------------------------------------------------------------
// FFT of filter rows, two real rows per block (z = k_{2d} + i*k_{2d+1}).
// ---------------------------------------------------------------------------
__global__ __launch_bounds__(512, 4) void kfft_kernel(
    const float* __restrict__ kfilt, float2* __restrict__ Kf)
{
    __shared__ float2 fb[4096];           // 32 KB
    const int d0 = blockIdx.x * 2;
    const float* k0 = kfilt + (size_t)d0 * LL;
    const float* k1 = k0 + LL;
    const float inv = 1.0f / 4096.0f;
    const int tid = threadIdx.x;
    for (int i = tid; i < 2048; i += 512) {
        fb[SWZ(i)]        = make_float2(k0[i] * inv, k1[i] * inv);
        fb[SWZ(i + 2048)] = make_float2(0.f, 0.f);
    }
    __syncthreads();
    fft4096_r8_ip<-1>(fb);
    float2* o0 = Kf + (size_t)d0 * KF_STRIDE;
    float2* o1 = o0 + KF_STRIDE;
    for (int k = tid; k <= 2048; k += 512) {
        const float2 z1 = fb[SWZ(k)];
        const float2 z2 = fb[SWZ((4096 - k) & 4095)];
        o0[k] = make_float2(0.5f * (z1.x + z2.x), 0.5f * (z1.y - z2.y));
        o1[k] = make_float2(0.5f * (z1.y + z2.y), 0.5f * (z2.x - z1.x));
    }
}

// ---------------------------------------------------------------------------
// Long conv, two real rows per block: z = v1 + i*v2, filter k is REAL.
// ---------------------------------------------------------------------------
__global__ __launch_bounds__(512, 4) void fftconv_kernel(
    float* __restrict__ vio, const float2* __restrict__ Kf,
    const float* __restrict__ fbias)
{
    __shared__ float2 fb[4096];           // 32 KB
    const int blk = blockIdx.x;          // [0, 2048)
    const int d   = blk >> 1;
    float* v1 = vio + (size_t)(2 * blk) * LL;
    float* v2 = v1 + LL;
    const int tid = threadIdx.x;
    for (int i = tid; i < 2048; i += 512) {
        fb[SWZ(i)]        = make_float2(v1[i], v2[i]);
        fb[SWZ(i + 2048)] = make_float2(0.f, 0.f);
    }
    __syncthreads();
    fft4096_r8_ip<-1>(fb);
    const float2* kf = Kf + (size_t)d * KF_STRIDE;
    for (int i = tid; i < 4096; i += 512) {
        float2 k;
        if (i <= 2048) k = kf[i];
        else { const float2 t = kf[4096 - i]; k = make_float2(t.x, -t.y); }
        fb[SWZ(i)] = cmul(fb[SWZ(i)], k);
    }
    __syncthreads();
    fft4096_r8_ip<1>(fb);
    const float bias = fbias[d];
    for (int i = tid; i < 2048; i += 512) {
        const float2 zy = fb[SWZ(i)];
        v1[i] = zy.x + bias * v1[i];
        v2[i] = zy.y + bias * v2[i];
    }
}

// ---------------------------------------------------------------------------
// gated_bf16(B,L,D) = bf16( y(D,B,L) * x0t(D,B,L) )  -- LDS 32x32 transpose
// ---------------------------------------------------------------------------
__global__ __launch_bounds__(256) void gate_transpose_kernel(
    const float* __restrict__ y, const bf16_t* __restrict__ x0t,
    bf16_t* __restrict__ g)
{
    __shared__ float tile[32][33];
    const int b  = blockIdx.z;
    const int l0 = blockIdx.x * 32;
    const int d0 = blockIdx.y * 32;
    const int tx  = threadIdx.x & 31;
    const int tyb = threadIdx.x >> 5;    // 0..7
    #pragma unroll
    for (int i = 0; i < 4; ++i) {
        const int dy = tyb + i * 8;
        const size_t src = ((size_t)(d0 + dy) * BB + b) * LL + l0 + tx;
        tile[dy][tx] = y[src] * (float)x0t[src];
    }
    __syncthreads();
    #pragma unroll
    for (int i = 0; i < 4; ++i) {
        const int ly = tyb + i * 8;
        g[((size_t)(b * LL + l0 + ly)) * DD + d0 + tx] = (bf16_t)tile[tx][ly];
    }
}

// ---------------------------------------------------------------------------
// Launch
// ---------------------------------------------------------------------------
extern "C" void kernel_launch(void* const* d_in, const int* in_sizes, int n_in,
                              void* d_out, int out_size, void* d_ws, size_t ws_size,
                              hipStream_t stream)
{
    (void)in_sizes; (void)n_in; (void)out_size; (void)ws_size;
    const float* x   = (const float*)d_in[0];
    const float* nw0 = (const float*)d_in[1];
    const float* ipw = (const float*)d_in[2];
    const float* ipb = (const float*)d_in[3];
    const float* sfw = (const float*)d_in[4];
    const float* sfb = (const float*)d_in[5];
    const float* w1  = (const float*)d_in[6];
    const float* b1  = (const float*)d_in[7];
    const float* f1  = (const float*)d_in[8];
    const float* w2  = (const float*)d_in[9];
    const float* b2  = (const float*)d_in[10];
    const float* f2  = (const float*)d_in[11];
    const float* w3  = (const float*)d_in[12];
    const float* fbv = (const float*)d_in[13];
    const float* opw = (const float*)d_in[14];
    const float* opb = (const float*)d_in[15];
    const float* nw1 = (const float*)d_in[16];
    const float* fw1 = (const float*)d_in[17];
    const float* fb1 = (const float*)d_in[18];
    const float* fw2 = (const float*)d_in[19];
    const float* fb2 = (const float*)d_in[20];
    float* out = (float*)d_out;

    float* ws = (float*)d_ws;
    bf16_t* utb    = (bf16_t*)ws;
    bf16_t* gatedb = (bf16_t*)ws;                       // 8,388,608 bf16
    float*  h      = ws + 4194304;                      // 8,388,608 f
    bf16_t* midb   = (bf16_t*)(ws + 12582912);          // 16,777,216 bf16
    bf16_t* xnb    = (bf16_t*)(ws + 25165824);          // 8M bf16 (also hn later)
    bf16_t* x0tb   = (bf16_t*)(ws + 29360128);          // 8,388,608 bf16 (D,B,L)
    float*  vio    = ws + 37748736;                     // 8,388,608 f (D,B,L)
    float*  kfilt  = ws + 46137344;                     // 2,097,152 f
    float2* Kf     = (float2*)(ws + 48234496);          // 1024 x KF_STRIDE cplx
    bf16_t* ipwb   = (bf16_t*)(ws + 52445184);          // 3,145,728 bf16
    bf16_t* opwb   = ipwb + 3145728;                    // 1,048,576 bf16
    bf16_t* fw1b   = opwb + 1048576;                    // 2,097,152 bf16
    bf16_t* fw2b   = fw1b + 2097152;                    // 2,097,152 bf16
    float*  h2t    = ws + 56639488;                     // (64, L) = 131,072 f

    // 0. weight casts (single launch, region-dispatched)
    cast_all_kernel<<<8192, 256, 0, stream>>>(ipw, opw, fw1, fw2,
                                              ipwb, opwb, fw1b, fw2b);
    // 1. implicit filter: MLP phase (h2t), modulation phase (kfilt), FFT (Kf)
    filtermlp_kernel<<<LL/32, 256, 0, stream>>>(w1, b1, f1, w2, b2, f2, h2t);
    filtermod_kernel<<<dim3(LL/256, DD/32), 256, 0, stream>>>(w3, h2t, kfilt);
    kfft_kernel<<<DD/2, 512, 0, stream>>>(kfilt, Kf);
    // 2. xn = bf16(rmsnorm(x, norm_in_w))
    rmsnorm_bf16_kernel<<<MM, 256, 0, stream>>>(x, nw0, xnb);
    // 3. u_t = in_proj_w @ xn^T + b (transposed output, bf16)
    gemm_mfma_kernel<0, true, true><<<dim3(MM/128, 3072/128), 256, 0, stream>>>(
        ipwb, xnb, ipb, nullptr, nullptr, utb, 3*DD, MM, DD);
    // 4. short filter -> x0t (D,B,L) bf16, vin (D,B,L) fp32
    shortfilter_kernel<<<DD, 256, 0, stream>>>(utb, sfw, sfb, x0tb, vio);
    // 5. vio <- causal_conv(vio, k) + filter_bias * vio   (2 rows per block)
    fftconv_kernel<<<BB*DD/2, 512, 0, stream>>>(vio, Kf, fbv);
    // 6. gated_bf16(B,L,D) = y * x0
    gate_transpose_kernel<<<dim3(LL/32, DD/32, BB), 256, 0, stream>>>(vio, x0tb, gatedb);
    // 7. h = gated @ out_proj_w^T + b + x   (M=8192, N=1024, K=1024)
    gemm_mfma_kernel<1, false><<<dim3(DD/128, MM/128), 256, 0, stream>>>(
        gatedb, opwb, opb, x, h, nullptr, MM, DD, DD);
    // 8. hn = bf16(rmsnorm(h, norm_w))
    rmsnorm_bf16_kernel<<<MM, 256, 0, stream>>>(h, nw1, xnb);
    // 9. mid = bf16(gelu(hn @ ffn_w1^T + b))  (M=8192, N=2048, K=1024)
    gemm_mfma_kernel<2, true><<<dim3(2*DD/128, MM/128), 256, 0, stream>>>(
        xnb, fw1b, fb1, nullptr, nullptr, midb, MM, 2*DD, DD);
    // 10. out = mid @ ffn_w2^T + b + h      (M=8192, N=1024, K=2048)
    gemm_mfma_kernel<1, false><<<dim3(DD/128, MM/128), 256, 0, stream>>>(
        midb, fw2b, fb2, h, out, nullptr, MM, DD, 2*DD);
}

// Round 6
// 514.794 us; speedup vs baseline: 1.2052x; 1.0491x over previous
//
#include <hip/hip_runtime.h>
#include <hip/hip_bf16.h>
#include <cstddef>

// ---------------------------------------------------------------------------
// Constants for this problem: B=4, L=2048, D=1024
// ---------------------------------------------------------------------------
#define BB 4
#define LL 2048
#define DD 1024
#define MM (BB*LL)          // 8192 tokens
#define KF_STRIDE 2056      // complex elements per Kf row (>= 2049, 16B-aligned)

// LDS bank swizzle for float2 arrays: spreads Stockham write streams across
// bank-pairs. Modifies bits 2-3 only (stays in range).
#define SWZ(a) ((a) ^ (((a) >> 4) & 12))

typedef __bf16 bf16_t;
typedef __attribute__((ext_vector_type(8))) __bf16 bf16x8;
typedef __attribute__((ext_vector_type(4))) __bf16 bf16x4;
typedef __attribute__((ext_vector_type(4))) float f32x4;

// async global->LDS, 16 bytes per lane (global_load_lds_dwordx4)
#define GLD_LDS16(gp, lp) __builtin_amdgcn_global_load_lds(                 \
    (const __attribute__((address_space(1))) unsigned int*)(gp),            \
    (__attribute__((address_space(3))) unsigned int*)(lp), 16, 0, 0)

__device__ __forceinline__ float gelu_tanh(float x) {
    const float c = 0.7978845608028654f;   // sqrt(2/pi)
    float t = tanhf(c * (x + 0.044715f * x * x * x));
    return 0.5f * x * (1.0f + t);
}

__device__ __forceinline__ float2 cmul(float2 a, float2 b) {
    return make_float2(a.x * b.x - a.y * b.y, a.x * b.y + a.y * b.x);
}
__device__ __forceinline__ float2 cadd(float2 a, float2 b) {
    return make_float2(a.x + b.x, a.y + b.y);
}
__device__ __forceinline__ float2 csub(float2 a, float2 b) {
    return make_float2(a.x - b.x, a.y - b.y);
}
// multiply by i*sigma (sigma = +-1)
__device__ __forceinline__ float2 cmuli(float2 z, float s) {
    return make_float2(-s * z.y, s * z.x);
}

// ---------------------------------------------------------------------------
// fp32 -> bf16 cast of all 4 weight matrices in ONE launch.
// ---------------------------------------------------------------------------
__global__ __launch_bounds__(256) void cast_all_kernel(
    const float* __restrict__ s0, const float* __restrict__ s1,
    const float* __restrict__ s2, const float* __restrict__ s3,
    bf16_t* __restrict__ d0, bf16_t* __restrict__ d1,
    bf16_t* __restrict__ d2, bf16_t* __restrict__ d3)
{
    const int b = blockIdx.x;
    const float* s; bf16_t* d; int base;
    if (b < 3072)      { s = s0; d = d0; base = b; }
    else if (b < 4096) { s = s1; d = d1; base = b - 3072; }
    else if (b < 6144) { s = s2; d = d2; base = b - 4096; }
    else               { s = s3; d = d3; base = b - 6144; }
    const int i = (base * 256 + threadIdx.x) * 4;
    const float4 v = *(const float4*)(s + i);
    bf16x4 o;
    o[0] = (bf16_t)v.x; o[1] = (bf16_t)v.y; o[2] = (bf16_t)v.z; o[3] = (bf16_t)v.w;
    *(bf16x4*)(d + i) = o;
}

// ---------------------------------------------------------------------------
// RMSNorm -> bf16 output: one block per row of 1024 floats
// ---------------------------------------------------------------------------
__global__ __launch_bounds__(256) void rmsnorm_bf16_kernel(
    const float* __restrict__ in, const float* __restrict__ w,
    bf16_t* __restrict__ out)
{
    const int row = blockIdx.x;
    const float4* ip = (const float4*)(in + (size_t)row * DD);
    float4 v = ip[threadIdx.x];
    float ss = v.x*v.x + v.y*v.y + v.z*v.z + v.w*v.w;
    #pragma unroll
    for (int off = 32; off > 0; off >>= 1) ss += __shfl_down(ss, off, 64);
    __shared__ float sums[4];
    const int wid = threadIdx.x >> 6;
    if ((threadIdx.x & 63) == 0) sums[wid] = ss;
    __syncthreads();
    const float tot = sums[0] + sums[1] + sums[2] + sums[3];
    const float scale = rsqrtf(tot * (1.0f / (float)DD) + 1e-8f);
    const float4 wv = ((const float4*)w)[threadIdx.x];
    bf16x4 o;
    o[0] = (bf16_t)(v.x * scale * wv.x);
    o[1] = (bf16_t)(v.y * scale * wv.y);
    o[2] = (bf16_t)(v.z * scale * wv.z);
    o[3] = (bf16_t)(v.w * scale * wv.w);
    *(bf16x4*)(out + (size_t)row * DD + threadIdx.x * 4) = o;
}

// ---------------------------------------------------------------------------
// bf16 MFMA GEMM: C(M,N) = epi(A(M,K) @ W(N,K)^T + bias) [+ res]
// 128x128 tile, BK=64, 256 thr (4 waves, 2x2), each wave 4x4 16x16x32 tiles.
// R10 schedule (VERIFIED 481.5us total): double-buffered 2-phase -- issue
// next-tile global_load_lds into buf^1 first, compute cur tile, ONE
// __syncthreads() per K-tile. s_setprio(1) around MFMA clusters.
// R14: XCD swizzle REVERTED (R5: default mapping already gives each XCD a
// 1/8 N-slice of W -> L2-resident; chunking gave each XCD ALL of W -> L2
// thrash, step9 46->103us).
// R14 NEW: LDS-staged epilogue. Old epilogue scattered 2B/4B stores in 32-64B
// segments -> partial-line writes -> write-allocate RMW (FETCH ~= WRITE_SIZE,
// ~130MB parasitic HBM fetch across the 4 GEMMs). Now: acc -> padded LDS tile
// (stride 136 bf16 / 132 f32: fq row-groups on distinct bank offsets) ->
// full-line 16B/lane vector writes. res reads also become coalesced.
// LDS chunk swizzle (staging, unchanged): chunk (row,q) at pos row*8+(q^(row&7));
// fragment ds_reads apply the same XOR -> 0 bank conflicts measured.
// EPI: 0 = bias, 1 = bias + residual, 2 = bias + tanh-GELU
// BIASROW: bias indexed by output row (for transposed-output GEMMs)
// ---------------------------------------------------------------------------
template<int EPI, bool BF16OUT, bool BIASROW = false>
__global__ __launch_bounds__(256) void gemm_mfma_kernel(
    const bf16_t* __restrict__ A,    // (M,K)
    const bf16_t* __restrict__ W,    // (N,K)
    const float* __restrict__ bias,  // (N) or (M) if BIASROW
    const float* __restrict__ res,   // (M,N) or nullptr
    float* __restrict__ Cf,          // fp32 out (if !BF16OUT)
    bf16_t* __restrict__ Cb,         // bf16 out (if BF16OUT)
    int M, int N, int K)
{
    __shared__ __align__(16) char smem[65536];
    bf16_t* AsB  = (bf16_t*)smem;              // [2][128*64] bf16 = 32 KB
    bf16_t* WsB  = (bf16_t*)(smem + 32768);    // [2][128*64] bf16 = 32 KB
    bf16_t* Cs16 = (bf16_t*)smem;              // epilogue reuse: 64x136 bf16
    float*  Cs32 = (float*)smem;               // epilogue reuse: 64x132 f32

    const int tid  = threadIdx.x;
    const int bm   = blockIdx.y * 128;
    const int bn   = blockIdx.x * 128;
    const int lane = tid & 63;
    const int wave = tid >> 6;
    const int wr   = (wave >> 1) * 64;
    const int wc   = (wave & 1) * 64;

    int srow[4], sqg[4];
    #pragma unroll
    for (int c = 0; c < 4; ++c) {
        const int p = c * 256 + tid;
        srow[c] = p >> 3;
        sqg[c]  = (((p & 7) ^ (srow[c] & 7)) << 3);
    }

    f32x4 acc[4][4] = {};

    const int fr = lane & 15;
    const int fc = (lane >> 4) * 8;

    const int nt = K >> 6;

    #pragma unroll
    for (int c = 0; c < 4; ++c) {
        GLD_LDS16(A + (size_t)(bm + srow[c]) * K + sqg[c],
                  AsB + c * 2048 + tid * 8);
        GLD_LDS16(W + (size_t)(bn + srow[c]) * K + sqg[c],
                  WsB + c * 2048 + tid * 8);
    }
    __syncthreads();

    int cur = 0;
    for (int t = 0; t < nt; ++t) {
        if (t + 1 < nt) {
            const int k0 = (t + 1) << 6;
            const int xo = (cur ^ 1) * 8192;
            #pragma unroll
            for (int c = 0; c < 4; ++c) {
                GLD_LDS16(A + (size_t)(bm + srow[c]) * K + k0 + sqg[c],
                          AsB + xo + c * 2048 + tid * 8);
                GLD_LDS16(W + (size_t)(bn + srow[c]) * K + k0 + sqg[c],
                          WsB + xo + c * 2048 + tid * 8);
            }
        }
        const int co = cur * 8192;
        #pragma unroll
        for (int ks = 0; ks < 64; ks += 32) {
            const int q = (ks + fc) >> 3;
            bf16x8 af[4], wf[4];
            #pragma unroll
            for (int i = 0; i < 4; ++i) {
                const int r = wr + i*16 + fr;
                af[i] = *(const bf16x8*)(AsB + co + r * 64 + ((q ^ (r & 7)) << 3));
            }
            #pragma unroll
            for (int j = 0; j < 4; ++j) {
                const int r = wc + j*16 + fr;
                wf[j] = *(const bf16x8*)(WsB + co + r * 64 + ((q ^ (r & 7)) << 3));
            }
            __builtin_amdgcn_s_setprio(1);
            #pragma unroll
            for (int i = 0; i < 4; ++i)
                #pragma unroll
                for (int j = 0; j < 4; ++j)
                    acc[i][j] = __builtin_amdgcn_mfma_f32_16x16x32_bf16(
                        af[i], wf[j], acc[i][j], 0, 0, 0);
            __builtin_amdgcn_s_setprio(0);
        }
        __syncthreads();
        cur ^= 1;
    }

    // ---- Epilogue: stage C through LDS, write full-line vectors ----
    // acc layout: col = wc + j*16 + (lane&15), row = wr + i*16 + (lane>>4)*4 + r
    const int fq = lane >> 4;
    #pragma unroll
    for (int p = 0; p < 2; ++p) {
        if ((wr >> 6) == p) {
            #pragma unroll
            for (int i = 0; i < 4; ++i) {
                #pragma unroll
                for (int j = 0; j < 4; ++j) {
                    const int col = wc + j*16 + fr;
                    const float bcol = BIASROW ? 0.0f : bias[bn + col];
                    #pragma unroll
                    for (int r = 0; r < 4; ++r) {
                        const int lr = i*16 + fq*4 + r;
                        float v = acc[i][j][r] +
                                  (BIASROW ? bias[bm + p*64 + lr] : bcol);
                        if constexpr (EPI == 2) v = gelu_tanh(v);
                        if constexpr (BF16OUT)
                            Cs16[lr * 136 + col] = (bf16_t)v;
                        else
                            Cs32[lr * 132 + col] = v;
                    }
                }
            }
        }
        __syncthreads();
        #pragma unroll
        for (int u = 0; u < 4; ++u) {
            const int id = u * 256 + tid;           // 0..1023
            const int lr = id >> 4;                  // 0..63
            const int c8 = (id & 15) * 8;            // 0..120
            const size_t grow = (size_t)(bm + p*64 + lr);
            if constexpr (BF16OUT) {
                const bf16x8 vv = *(const bf16x8*)(Cs16 + lr * 136 + c8);
                *(bf16x8*)(Cb + grow * N + bn + c8) = vv;
            } else {
                float4 v0 = *(const float4*)(Cs32 + lr * 132 + c8);
                float4 v1 = *(const float4*)(Cs32 + lr * 132 + c8 + 4);
                if constexpr (EPI == 1) {
                    const float4 r0 = *(const float4*)(res + grow * N + bn + c8);
                    const float4 r1 = *(const float4*)(res + grow * N + bn + c8 + 4);
                    v0.x += r0.x; v0.y += r0.y; v0.z += r0.z; v0.w += r0.w;
                    v1.x += r1.x; v1.y += r1.y; v1.z += r1.z; v1.w += r1.w;
                }
                *(float4*)(Cf + grow * N + bn + c8)     = v0;
                *(float4*)(Cf + grow * N + bn + c8 + 4) = v1;
            }
        }
        if (p == 0) __syncthreads();
    }
}

// ---------------------------------------------------------------------------
// Depthwise causal k=3 short filter on u_t (3D, M) channel-major bf16.
// Vectorized bf16x8 loads (16 B/lane), 8 positions per thread, 16-B stores.
// ---------------------------------------------------------------------------
__global__ __launch_bounds__(256) void shortfilter_kernel(
    const bf16_t* __restrict__ ut, const float* __restrict__ sw,
    const float* __restrict__ sb, bf16_t* __restrict__ x0t,
    float* __restrict__ vin)
{
    const int d = blockIdx.x;             // 0..1023
    const int c0 = d, c1 = DD + d, c2 = 2 * DD + d;
    const float w0a = sw[c0*3+0], w0b = sw[c0*3+1], w0c = sw[c0*3+2], b0 = sb[c0];
    const float w1a = sw[c1*3+0], w1b = sw[c1*3+1], w1c = sw[c1*3+2], b1 = sb[c1];
    const float w2a = sw[c2*3+0], w2b = sw[c2*3+1], w2c = sw[c2*3+2], b2 = sb[c2];
    const bf16_t* r0 = ut + (size_t)c0 * MM;
    const bf16_t* r1 = ut + (size_t)c1 * MM;
    const bf16_t* r2 = ut + (size_t)c2 * MM;
    bf16_t* o0 = x0t + (size_t)d * MM;
    float*  o1 = vin + (size_t)d * MM;
    for (int m0 = threadIdx.x * 8; m0 < MM; m0 += 2048) {
        const int l0 = m0 & (LL - 1);
        const bf16x8 a0 = *(const bf16x8*)(r0 + m0);
        const bf16x8 a1 = *(const bf16x8*)(r1 + m0);
        const bf16x8 a2 = *(const bf16x8*)(r2 + m0);
        float u0[10], u1[10], u2[10];
        u0[0] = u0[1] = u1[0] = u1[1] = u2[0] = u2[1] = 0.0f;
        if (l0 != 0) {
            u0[0] = (float)r0[m0-2]; u0[1] = (float)r0[m0-1];
            u1[0] = (float)r1[m0-2]; u1[1] = (float)r1[m0-1];
            u2[0] = (float)r2[m0-2]; u2[1] = (float)r2[m0-1];
        }
        #pragma unroll
        for (int i = 0; i < 8; ++i) {
            u0[i+2] = (float)a0[i];
            u1[i+2] = (float)a1[i];
            u2[i+2] = (float)a2[i];
        }
        bf16x8 ov;
        float v1o[8];
        #pragma unroll
        for (int i = 0; i < 8; ++i) {
            const float v0 = w0c*u0[i+2] + w0b*u0[i+1] + w0a*u0[i] + b0;
            const float v1 = w1c*u1[i+2] + w1b*u1[i+1] + w1a*u1[i] + b1;
            const float v2 = w2c*u2[i+2] + w2b*u2[i+1] + w2a*u2[i] + b2;
            ov[i] = (bf16_t)v0;
            v1o[i] = v2 * v1;
        }
        *(bf16x8*)(o0 + m0) = ov;
        *(float4*)(o1 + m0)     = make_float4(v1o[0], v1o[1], v1o[2], v1o[3]);
        *(float4*)(o1 + m0 + 4) = make_float4(v1o[4], v1o[5], v1o[6], v1o[7]);
    }
}

// ---------------------------------------------------------------------------
// Implicit filter MLP, phase 1: h2t (64, L).
// Block = 32 l-positions x 64 j, grid = 64 blocks.
// ---------------------------------------------------------------------------
__global__ __launch_bounds__(256) void filtermlp_kernel(
    const float* __restrict__ w1, const float* __restrict__ b1,
    const float* __restrict__ f1, const float* __restrict__ w2,
    const float* __restrict__ b2, const float* __restrict__ f2,
    float* __restrict__ h2t)
{
    __shared__ float w2s[64 * 64];      // 16 KB
    __shared__ float h1s[64][32];       // 8 KB, [j][l]
    const int tid = threadIdx.x;
    #pragma unroll
    for (int i = 0; i < 4; ++i)
        ((float4*)w2s)[tid + 256 * i] = ((const float4*)w2)[tid + 256 * i];

    const int l0 = blockIdx.x * 32;
    const int l  = tid & 31;
    const float fl = (float)(l0 + l);
    const float t   = fl * (1.0f / (float)(LL - 1));
    const float ang = 1e-4f * 6.283185307179586f * fl * (1.0f / (float)LL);
    const float z0 = t, z1 = cosf(ang), z2 = -sinf(ang);

    #pragma unroll
    for (int i = 0; i < 8; ++i) {
        const int j = (tid >> 5) + 8 * i;
        const float s = w1[j*3+0]*z0 + w1[j*3+1]*z1 + w1[j*3+2]*z2 + b1[j];
        h1s[j][l] = sinf(f1[j] * s);
    }
    __syncthreads();

    const int jb = (tid >> 5) * 8;
    float acc[8];
    #pragma unroll
    for (int i = 0; i < 8; ++i) acc[i] = b2[jb + i];
    #pragma unroll
    for (int jj = 0; jj < 64; jj += 4) {
        const float h0 = h1s[jj + 0][l];
        const float h1v = h1s[jj + 1][l];
        const float h2v = h1s[jj + 2][l];
        const float h3 = h1s[jj + 3][l];
        #pragma unroll
        for (int i = 0; i < 8; ++i) {
            const float4 wv = *(const float4*)&w2s[(jb + i) * 64 + jj];
            acc[i] += wv.x * h0 + wv.y * h1v + wv.z * h2v + wv.w * h3;
        }
    }
    #pragma unroll
    for (int i = 0; i < 8; ++i)
        h2t[(size_t)(jb + i) * LL + l0 + l] = sinf(f2[jb + i] * acc[i]);
}

// ---------------------------------------------------------------------------
// Implicit filter, phase 2: kfilt[d][l] = (w3[d,:] . h2t[:,l]) * exp(-t|delta_d|)
// ---------------------------------------------------------------------------
__global__ __launch_bounds__(256) void filtermod_kernel(
    const float* __restrict__ w3, const float* __restrict__ h2t,
    float* __restrict__ kfilt)
{
    __shared__ float w3s[32 * 64];      // 8 KB
    const int d0 = blockIdx.y * 32;
    const int l  = blockIdx.x * 256 + threadIdx.x;
    for (int i = threadIdx.x; i < 32 * 64; i += 256) w3s[i] = w3[d0 * 64 + i];
    __syncthreads();
    float acc[32] = {};
    for (int j = 0; j < 64; ++j) {
        const float v = h2t[j * LL + l];
        #pragma unroll
        for (int dd = 0; dd < 32; ++dd) acc[dd] += w3s[dd*64 + j] * v;
    }
    const float t = (float)l / (float)(LL - 1);
    const float min_decay = -3.0701134573253944f;   // ln(1e-2)/1.5
    const float max_decay = -15.350567286626972f;   // ln(1e-2)/0.3
    #pragma unroll
    for (int dd = 0; dd < 32; ++dd) {
        const int d = d0 + dd;
        const float delta = fabsf(min_decay + (max_decay - min_decay) * (float)d / (float)(DD - 1));
        kfilt[(size_t)d * LL + l] = acc[dd] * expf(-t * delta);
    }
}

// ---------------------------------------------------------------------------
// 4096-point complex Stockham RADIX-8 FFT, in-place in 32 KB LDS.
// ---------------------------------------------------------------------------
template<int SIGN>
__device__ __forceinline__ void fft4096_r8_ip(float2* __restrict__ buf)
{
    const float fs = (float)SIGN;
    const float RH = 0.7071067811865476f;   // sqrt(2)/2
    const int tid = threadIdx.x;            // 0..511
    #pragma unroll
    for (int t = 0; t < 4; ++t) {
        const int ls = 3 * t;               // log2(stride): 0,3,6,9
        const int s  = 1 << ls;
        const float theta = fs * 6.283185307179586f / (float)(4096 >> ls);
        float2 a[8];
        #pragma unroll
        for (int m = 0; m < 8; ++m) a[m] = buf[SWZ(tid + m * 512)];
        __syncthreads();
        const int p = tid >> ls;
        const int q = tid & (s - 1);
        float sn, cs;
        __sincosf(theta * (float)p, &sn, &cs);
        const float2 W1 = make_float2(cs, sn);
        const float2 W2 = cmul(W1, W1);
        const float2 W3 = cmul(W2, W1);
        const float2 W4 = cmul(W2, W2);
        const float2 W5 = cmul(W4, W1);
        const float2 W6 = cmul(W4, W2);
        const float2 W7 = cmul(W4, W3);
        const float2 es = cadd(a[0], a[4]), ed = csub(a[0], a[4]);
        const float2 fs2 = cadd(a[2], a[6]), fd = csub(a[2], a[6]);
        const float2 E0 = cadd(es, fs2);
        const float2 E1 = cadd(ed, cmuli(fd, fs));
        const float2 E2 = csub(es, fs2);
        const float2 E3 = csub(ed, cmuli(fd, fs));
        const float2 os = cadd(a[1], a[5]), od = csub(a[1], a[5]);
        const float2 gs = cadd(a[3], a[7]), gd = csub(a[3], a[7]);
        const float2 O0 = cadd(os, gs);
        const float2 O1 = cadd(od, cmuli(gd, fs));
        const float2 O2 = csub(os, gs);
        const float2 O3 = csub(od, cmuli(gd, fs));
        const float2 T0 = O0;
        const float2 T1 = make_float2(RH * (O1.x - fs * O1.y), RH * (fs * O1.x + O1.y));
        const float2 T2 = cmuli(O2, fs);
        const float2 T3 = make_float2(RH * (-O3.x - fs * O3.y), RH * (fs * O3.x - O3.y));
        const int o = q + (p << (ls + 3));
        buf[SWZ(o)]         = cadd(E0, T0);
        buf[SWZ(o + s)]     = cmul(W1, cadd(E1, T1));
        buf[SWZ(o + 2*s)]   = cmul(W2, cadd(E2, T2));
        buf[SWZ(o + 3*s)]   = cmul(W3, cadd(E3, T3));
        buf[SWZ(o + 4*s)]   = cmul(W4, csub(E0, T0));
        buf[SWZ(o + 5*s)]   = cmul(W5, csub(E1, T1));
        buf[SWZ(o + 6*s)]   = cmul(W6, csub(E2, T2));
        buf[SWZ(o + 7*s)]   = cmul(W7, csub(E3, T3));
        __syncthreads();
    }
}

// ---------------------------------------------------------------------------
// FFT of filter rows, two real rows per block (z = k_{2d} + i*k_{2d+1}).
// ---------------------------------------------------------------------------
__global__ __launch_bounds__(512, 4) void kfft_kernel(
    const float* __restrict__ kfilt, float2* __restrict__ Kf)
{
    __shared__ float2 fb[4096];           // 32 KB
    const int d0 = blockIdx.x * 2;
    const float* k0 = kfilt + (size_t)d0 * LL;
    const float* k1 = k0 + LL;
    const float inv = 1.0f / 4096.0f;
    const int tid = threadIdx.x;
    for (int i = tid; i < 2048; i += 512) {
        fb[SWZ(i)]        = make_float2(k0[i] * inv, k1[i] * inv);
        fb[SWZ(i + 2048)] = make_float2(0.f, 0.f);
    }
    __syncthreads();
    fft4096_r8_ip<-1>(fb);
    float2* o0 = Kf + (size_t)d0 * KF_STRIDE;
    float2* o1 = o0 + KF_STRIDE;
    for (int k = tid; k <= 2048; k += 512) {
        const float2 z1 = fb[SWZ(k)];
        const float2 z2 = fb[SWZ((4096 - k) & 4095)];
        o0[k] = make_float2(0.5f * (z1.x + z2.x), 0.5f * (z1.y - z2.y));
        o1[k] = make_float2(0.5f * (z1.y + z2.y), 0.5f * (z2.x - z1.x));
    }
}

// ---------------------------------------------------------------------------
// Long conv, two real rows per block: z = v1 + i*v2, filter k is REAL.
// ---------------------------------------------------------------------------
__global__ __launch_bounds__(512, 4) void fftconv_kernel(
    float* __restrict__ vio, const float2* __restrict__ Kf,
    const float* __restrict__ fbias)
{
    __shared__ float2 fb[4096];           // 32 KB
    const int blk = blockIdx.x;          // [0, 2048)
    const int d   = blk >> 1;
    float* v1 = vio + (size_t)(2 * blk) * LL;
    float* v2 = v1 + LL;
    const int tid = threadIdx.x;
    for (int i = tid; i < 2048; i += 512) {
        fb[SWZ(i)]        = make_float2(v1[i], v2[i]);
        fb[SWZ(i + 2048)] = make_float2(0.f, 0.f);
    }
    __syncthreads();
    fft4096_r8_ip<-1>(fb);
    const float2* kf = Kf + (size_t)d * KF_STRIDE;
    for (int i = tid; i < 4096; i += 512) {
        float2 k;
        if (i <= 2048) k = kf[i];
        else { const float2 t = kf[4096 - i]; k = make_float2(t.x, -t.y); }
        fb[SWZ(i)] = cmul(fb[SWZ(i)], k);
    }
    __syncthreads();
    fft4096_r8_ip<1>(fb);
    const float bias = fbias[d];
    for (int i = tid; i < 2048; i += 512) {
        const float2 zy = fb[SWZ(i)];
        v1[i] = zy.x + bias * v1[i];
        v2[i] = zy.y + bias * v2[i];
    }
}

// ---------------------------------------------------------------------------
// gated_bf16(B,L,D) = bf16( y(D,B,L) * x0t(D,B,L) )  -- LDS 32x32 transpose
// ---------------------------------------------------------------------------
__global__ __launch_bounds__(256) void gate_transpose_kernel(
    const float* __restrict__ y, const bf16_t* __restrict__ x0t,
    bf16_t* __restrict__ g)
{
    __shared__ float tile[32][33];
    const int b  = blockIdx.z;
    const int l0 = blockIdx.x * 32;
    const int d0 = blockIdx.y * 32;
    const int tx  = threadIdx.x & 31;
    const int tyb = threadIdx.x >> 5;    // 0..7
    #pragma unroll
    for (int i = 0; i < 4; ++i) {
        const int dy = tyb + i * 8;
        const size_t src = ((size_t)(d0 + dy) * BB + b) * LL + l0 + tx;
        tile[dy][tx] = y[src] * (float)x0t[src];
    }
    __syncthreads();
    #pragma unroll
    for (int i = 0; i < 4; ++i) {
        const int ly = tyb + i * 8;
        g[((size_t)(b * LL + l0 + ly)) * DD + d0 + tx] = (bf16_t)tile[tx][ly];
    }
}

// ---------------------------------------------------------------------------
// Launch
// ---------------------------------------------------------------------------
extern "C" void kernel_launch(void* const* d_in, const int* in_sizes, int n_in,
                              void* d_out, int out_size, void* d_ws, size_t ws_size,
                              hipStream_t stream)
{
    (void)in_sizes; (void)n_in; (void)out_size; (void)ws_size;
    const float* x   = (const float*)d_in[0];
    const float* nw0 = (const float*)d_in[1];
    const float* ipw = (const float*)d_in[2];
    const float* ipb = (const float*)d_in[3];
    const float* sfw = (const float*)d_in[4];
    const float* sfb = (const float*)d_in[5];
    const float* w1  = (const float*)d_in[6];
    const float* b1  = (const float*)d_in[7];
    const float* f1  = (const float*)d_in[8];
    const float* w2  = (const float*)d_in[9];
    const float* b2  = (const float*)d_in[10];
    const float* f2  = (const float*)d_in[11];
    const float* w3  = (const float*)d_in[12];
    const float* fbv = (const float*)d_in[13];
    const float* opw = (const float*)d_in[14];
    const float* opb = (const float*)d_in[15];
    const float* nw1 = (const float*)d_in[16];
    const float* fw1 = (const float*)d_in[17];
    const float* fb1 = (const float*)d_in[18];
    const float* fw2 = (const float*)d_in[19];
    const float* fb2 = (const float*)d_in[20];
    float* out = (float*)d_out;

    float* ws = (float*)d_ws;
    bf16_t* utb    = (bf16_t*)ws;
    bf16_t* gatedb = (bf16_t*)ws;                       // 8,388,608 bf16
    float*  h      = ws + 4194304;                      // 8,388,608 f
    bf16_t* midb   = (bf16_t*)(ws + 12582912);          // 16,777,216 bf16
    bf16_t* xnb    = (bf16_t*)(ws + 25165824);          // 8M bf16 (also hn later)
    bf16_t* x0tb   = (bf16_t*)(ws + 29360128);          // 8,388,608 bf16 (D,B,L)
    float*  vio    = ws + 37748736;                     // 8,388,608 f (D,B,L)
    float*  kfilt  = ws + 46137344;                     // 2,097,152 f
    float2* Kf     = (float2*)(ws + 48234496);          // 1024 x KF_STRIDE cplx
    bf16_t* ipwb   = (bf16_t*)(ws + 52445184);          // 3,145,728 bf16
    bf16_t* opwb   = ipwb + 3145728;                    // 1,048,576 bf16
    bf16_t* fw1b   = opwb + 1048576;                    // 2,097,152 bf16
    bf16_t* fw2b   = fw1b + 2097152;                    // 2,097,152 bf16
    float*  h2t    = ws + 56639488;                     // (64, L) = 131,072 f

    // 0. weight casts (single launch, region-dispatched)
    cast_all_kernel<<<8192, 256, 0, stream>>>(ipw, opw, fw1, fw2,
                                              ipwb, opwb, fw1b, fw2b);
    // 1. implicit filter: MLP phase (h2t), modulation phase (kfilt), FFT (Kf)
    filtermlp_kernel<<<LL/32, 256, 0, stream>>>(w1, b1, f1, w2, b2, f2, h2t);
    filtermod_kernel<<<dim3(LL/256, DD/32), 256, 0, stream>>>(w3, h2t, kfilt);
    kfft_kernel<<<DD/2, 512, 0, stream>>>(kfilt, Kf);
    // 2. xn = bf16(rmsnorm(x, norm_in_w))
    rmsnorm_bf16_kernel<<<MM, 256, 0, stream>>>(x, nw0, xnb);
    // 3. u_t = in_proj_w @ xn^T + b (transposed output, bf16)
    gemm_mfma_kernel<0, true, true><<<dim3(MM/128, 3072/128), 256, 0, stream>>>(
        ipwb, xnb, ipb, nullptr, nullptr, utb, 3*DD, MM, DD);
    // 4. short filter -> x0t (D,B,L) bf16, vin (D,B,L) fp32
    shortfilter_kernel<<<DD, 256, 0, stream>>>(utb, sfw, sfb, x0tb, vio);
    // 5. vio <- causal_conv(vio, k) + filter_bias * vio   (2 rows per block)
    fftconv_kernel<<<BB*DD/2, 512, 0, stream>>>(vio, Kf, fbv);
    // 6. gated_bf16(B,L,D) = y * x0
    gate_transpose_kernel<<<dim3(LL/32, DD/32, BB), 256, 0, stream>>>(vio, x0tb, gatedb);
    // 7. h = gated @ out_proj_w^T + b + x   (M=8192, N=1024, K=1024)
    gemm_mfma_kernel<1, false><<<dim3(DD/128, MM/128), 256, 0, stream>>>(
        gatedb, opwb, opb, x, h, nullptr, MM, DD, DD);
    // 8. hn = bf16(rmsnorm(h, norm_w))
    rmsnorm_bf16_kernel<<<MM, 256, 0, stream>>>(h, nw1, xnb);
    // 9. mid = bf16(gelu(hn @ ffn_w1^T + b))  (M=8192, N=2048, K=1024)
    gemm_mfma_kernel<2, true><<<dim3(2*DD/128, MM/128), 256, 0, stream>>>(
        xnb, fw1b, fb1, nullptr, nullptr, midb, MM, 2*DD, DD);
    // 10. out = mid @ ffn_w2^T + b + h      (M=8192, N=1024, K=2048)
    gemm_mfma_kernel<1, false><<<dim3(DD/128, MM/128), 256, 0, stream>>>(
        midb, fw2b, fb2, h, out, nullptr, MM, DD, 2*DD);
}

// Round 7
// 476.179 us; speedup vs baseline: 1.3029x; 1.0811x over previous
//
#include <hip/hip_runtime.h>
#include <hip/hip_bf16.h>
#include <cstddef>

// ---------------------------------------------------------------------------
// Constants for this problem: B=4, L=2048, D=1024
// ---------------------------------------------------------------------------
#define BB 4
#define LL 2048
#define DD 1024
#define MM (BB*LL)          // 8192 tokens
#define KF_STRIDE 2056      // complex elements per Kf row (>= 2049, 16B-aligned)

// LDS bank swizzle for float2 arrays: spreads Stockham write streams across
// bank-pairs. Modifies bits 2-3 only (stays in range).
#define SWZ(a) ((a) ^ (((a) >> 4) & 12))

typedef __bf16 bf16_t;
typedef __attribute__((ext_vector_type(8))) __bf16 bf16x8;
typedef __attribute__((ext_vector_type(4))) __bf16 bf16x4;
typedef __attribute__((ext_vector_type(4))) float f32x4;

// async global->LDS, 16 bytes per lane (global_load_lds_dwordx4)
#define GLD_LDS16(gp, lp) __builtin_amdgcn_global_load_lds(                 \
    (const __attribute__((address_space(1))) unsigned int*)(gp),            \
    (__attribute__((address_space(3))) unsigned int*)(lp), 16, 0, 0)

__device__ __forceinline__ float gelu_tanh(float x) {
    const float c = 0.7978845608028654f;   // sqrt(2/pi)
    float t = tanhf(c * (x + 0.044715f * x * x * x));
    return 0.5f * x * (1.0f + t);
}

__device__ __forceinline__ float2 cmul(float2 a, float2 b) {
    return make_float2(a.x * b.x - a.y * b.y, a.x * b.y + a.y * b.x);
}
__device__ __forceinline__ float2 cadd(float2 a, float2 b) {
    return make_float2(a.x + b.x, a.y + b.y);
}
__device__ __forceinline__ float2 csub(float2 a, float2 b) {
    return make_float2(a.x - b.x, a.y - b.y);
}
// multiply by i*sigma (sigma = +-1)
__device__ __forceinline__ float2 cmuli(float2 z, float s) {
    return make_float2(-s * z.y, s * z.x);
}

// ---------------------------------------------------------------------------
// fp32 -> bf16 cast of all 4 weight matrices in ONE launch.
// ---------------------------------------------------------------------------
__global__ __launch_bounds__(256) void cast_all_kernel(
    const float* __restrict__ s0, const float* __restrict__ s1,
    const float* __restrict__ s2, const float* __restrict__ s3,
    bf16_t* __restrict__ d0, bf16_t* __restrict__ d1,
    bf16_t* __restrict__ d2, bf16_t* __restrict__ d3)
{
    const int b = blockIdx.x;
    const float* s; bf16_t* d; int base;
    if (b < 3072)      { s = s0; d = d0; base = b; }
    else if (b < 4096) { s = s1; d = d1; base = b - 3072; }
    else if (b < 6144) { s = s2; d = d2; base = b - 4096; }
    else               { s = s3; d = d3; base = b - 6144; }
    const int i = (base * 256 + threadIdx.x) * 4;
    const float4 v = *(const float4*)(s + i);
    bf16x4 o;
    o[0] = (bf16_t)v.x; o[1] = (bf16_t)v.y; o[2] = (bf16_t)v.z; o[3] = (bf16_t)v.w;
    *(bf16x4*)(d + i) = o;
}

// ---------------------------------------------------------------------------
// RMSNorm -> bf16 output: one block per row of 1024 floats
// ---------------------------------------------------------------------------
__global__ __launch_bounds__(256) void rmsnorm_bf16_kernel(
    const float* __restrict__ in, const float* __restrict__ w,
    bf16_t* __restrict__ out)
{
    const int row = blockIdx.x;
    const float4* ip = (const float4*)(in + (size_t)row * DD);
    float4 v = ip[threadIdx.x];
    float ss = v.x*v.x + v.y*v.y + v.z*v.z + v.w*v.w;
    #pragma unroll
    for (int off = 32; off > 0; off >>= 1) ss += __shfl_down(ss, off, 64);
    __shared__ float sums[4];
    const int wid = threadIdx.x >> 6;
    if ((threadIdx.x & 63) == 0) sums[wid] = ss;
    __syncthreads();
    const float tot = sums[0] + sums[1] + sums[2] + sums[3];
    const float scale = rsqrtf(tot * (1.0f / (float)DD) + 1e-8f);
    const float4 wv = ((const float4*)w)[threadIdx.x];
    bf16x4 o;
    o[0] = (bf16_t)(v.x * scale * wv.x);
    o[1] = (bf16_t)(v.y * scale * wv.y);
    o[2] = (bf16_t)(v.z * scale * wv.z);
    o[3] = (bf16_t)(v.w * scale * wv.w);
    *(bf16x4*)(out + (size_t)row * DD + threadIdx.x * 4) = o;
}

// ---------------------------------------------------------------------------
// bf16 MFMA GEMM: C(M,N) = epi(A(M,K) @ W(N,K)^T + bias) [+ res]
// 128x128 tile, BK=64, R2-VERIFIED schedule: double-buffered 2-phase --
// issue next-tile global_load_lds into buf^1 first, compute cur tile, ONE
// __syncthreads() per K-tile. setprio(1) around MFMA. Direct epilogue
// (R6's LDS-staged epilogue REVERTED: cut RMW fetch but cost > benefit --
// HBM was 17% of peak, not the critical path).
// R15 CHANGE: 512 threads / 8 waves (2x4), per-wave tile 64x32, acc 4x2.
// Rationale: occupancy was ~19% (2 waves/SIMD) in EVERY config because
// per-wave regs (~88 VGPR + 64 acc = ~152) > 128 -> 2 waves/SIMD (m69
// steps at 64/128/256). Halving the accumulator (+smaller frags) brings
// per-wave regs under 128 -> 4 waves/SIMD, 16 waves/CU: doubles the TLP
// available to hide the per-K-tile barrier drain. Block-level FLOPs,
// staging volume, barrier count, swizzle, epilogue pattern: unchanged.
// EPI: 0 = bias, 1 = bias + residual, 2 = bias + tanh-GELU
// BIASROW: bias indexed by output row (for transposed-output GEMMs)
// ---------------------------------------------------------------------------
template<int EPI, bool BF16OUT, bool BIASROW = false>
__global__ __launch_bounds__(512) void gemm_mfma_kernel(
    const bf16_t* __restrict__ A,    // (M,K)
    const bf16_t* __restrict__ W,    // (N,K)
    const float* __restrict__ bias,  // (N) or (M) if BIASROW
    const float* __restrict__ res,   // (M,N) or nullptr
    float* __restrict__ Cf,          // fp32 out (if !BF16OUT)
    bf16_t* __restrict__ Cb,         // bf16 out (if BF16OUT)
    int M, int N, int K)
{
    __shared__ __align__(16) bf16_t As[2][128 * 64];   // 32 KB
    __shared__ __align__(16) bf16_t Ws[2][128 * 64];   // 32 KB
    const int tid  = threadIdx.x;                      // 0..511
    const int bm   = blockIdx.y * 128;
    const int bn   = blockIdx.x * 128;
    const int lane = tid & 63;
    const int wave = tid >> 6;                         // 0..7
    const int wr   = (wave >> 2) * 64;                 // row-group: 0 / 64
    const int wc   = (wave & 3) * 32;                  // col-group: 0/32/64/96

    // staging: 1024 16-B chunks per matrix; 2 chunks per thread.
    // chunk pos p -> row = p>>3, global chunk q = (p&7)^(row&7)
    int srow[2], sqg[2];
    #pragma unroll
    for (int c = 0; c < 2; ++c) {
        const int p = c * 512 + tid;
        srow[c] = p >> 3;
        sqg[c]  = (((p & 7) ^ (srow[c] & 7)) << 3);
    }

    f32x4 acc[4][2] = {};

    const int fr = lane & 15;
    const int fc = (lane >> 4) * 8;

    const int nt = K >> 6;

    #pragma unroll
    for (int c = 0; c < 2; ++c) {
        GLD_LDS16(A + (size_t)(bm + srow[c]) * K + sqg[c],
                  &As[0][c * 4096 + tid * 8]);
        GLD_LDS16(W + (size_t)(bn + srow[c]) * K + sqg[c],
                  &Ws[0][c * 4096 + tid * 8]);
    }
    __syncthreads();

    int cur = 0;
    for (int t = 0; t < nt; ++t) {
        if (t + 1 < nt) {
            const int k0 = (t + 1) << 6;
            #pragma unroll
            for (int c = 0; c < 2; ++c) {
                GLD_LDS16(A + (size_t)(bm + srow[c]) * K + k0 + sqg[c],
                          &As[cur ^ 1][c * 4096 + tid * 8]);
                GLD_LDS16(W + (size_t)(bn + srow[c]) * K + k0 + sqg[c],
                          &Ws[cur ^ 1][c * 4096 + tid * 8]);
            }
        }
        #pragma unroll
        for (int ks = 0; ks < 64; ks += 32) {
            const int q = (ks + fc) >> 3;
            bf16x8 af[4], wf[2];
            #pragma unroll
            for (int i = 0; i < 4; ++i) {
                const int r = wr + i*16 + fr;
                af[i] = *(const bf16x8*)(&As[cur][r * 64 + ((q ^ (r & 7)) << 3)]);
            }
            #pragma unroll
            for (int j = 0; j < 2; ++j) {
                const int r = wc + j*16 + fr;
                wf[j] = *(const bf16x8*)(&Ws[cur][r * 64 + ((q ^ (r & 7)) << 3)]);
            }
            __builtin_amdgcn_s_setprio(1);
            #pragma unroll
            for (int i = 0; i < 4; ++i)
                #pragma unroll
                for (int j = 0; j < 2; ++j)
                    acc[i][j] = __builtin_amdgcn_mfma_f32_16x16x32_bf16(
                        af[i], wf[j], acc[i][j], 0, 0, 0);
            __builtin_amdgcn_s_setprio(0);
        }
        __syncthreads();
        cur ^= 1;
    }

    // Epilogue (R2-verified pattern). C/D: col = lane&15, row = (lane>>4)*4+reg
    const int fq = lane >> 4;
    #pragma unroll
    for (int i = 0; i < 4; ++i) {
        const int row0 = bm + wr + i*16 + fq*4;
        #pragma unroll
        for (int j = 0; j < 2; ++j) {
            const int col = bn + wc + j*16 + fr;
            const float bcol = BIASROW ? 0.0f : bias[col];
            #pragma unroll
            for (int r = 0; r < 4; ++r) {
                float v = acc[i][j][r] + (BIASROW ? bias[row0 + r] : bcol);
                if constexpr (EPI == 2) v = gelu_tanh(v);
                if constexpr (EPI == 1) v += res[(size_t)(row0 + r) * N + col];
                if constexpr (BF16OUT)
                    Cb[(size_t)(row0 + r) * N + col] = (bf16_t)v;
                else
                    Cf[(size_t)(row0 + r) * N + col] = v;
            }
        }
    }
}

// ---------------------------------------------------------------------------
// Depthwise causal k=3 short filter on u_t (3D, M) channel-major bf16.
// Vectorized bf16x8 loads (16 B/lane), 8 positions per thread, 16-B stores.
// ---------------------------------------------------------------------------
__global__ __launch_bounds__(256) void shortfilter_kernel(
    const bf16_t* __restrict__ ut, const float* __restrict__ sw,
    const float* __restrict__ sb, bf16_t* __restrict__ x0t,
    float* __restrict__ vin)
{
    const int d = blockIdx.x;             // 0..1023
    const int c0 = d, c1 = DD + d, c2 = 2 * DD + d;
    const float w0a = sw[c0*3+0], w0b = sw[c0*3+1], w0c = sw[c0*3+2], b0 = sb[c0];
    const float w1a = sw[c1*3+0], w1b = sw[c1*3+1], w1c = sw[c1*3+2], b1 = sb[c1];
    const float w2a = sw[c2*3+0], w2b = sw[c2*3+1], w2c = sw[c2*3+2], b2 = sb[c2];
    const bf16_t* r0 = ut + (size_t)c0 * MM;
    const bf16_t* r1 = ut + (size_t)c1 * MM;
    const bf16_t* r2 = ut + (size_t)c2 * MM;
    bf16_t* o0 = x0t + (size_t)d * MM;
    float*  o1 = vin + (size_t)d * MM;
    for (int m0 = threadIdx.x * 8; m0 < MM; m0 += 2048) {
        const int l0 = m0 & (LL - 1);
        const bf16x8 a0 = *(const bf16x8*)(r0 + m0);
        const bf16x8 a1 = *(const bf16x8*)(r1 + m0);
        const bf16x8 a2 = *(const bf16x8*)(r2 + m0);
        float u0[10], u1[10], u2[10];
        u0[0] = u0[1] = u1[0] = u1[1] = u2[0] = u2[1] = 0.0f;
        if (l0 != 0) {
            u0[0] = (float)r0[m0-2]; u0[1] = (float)r0[m0-1];
            u1[0] = (float)r1[m0-2]; u1[1] = (float)r1[m0-1];
            u2[0] = (float)r2[m0-2]; u2[1] = (float)r2[m0-1];
        }
        #pragma unroll
        for (int i = 0; i < 8; ++i) {
            u0[i+2] = (float)a0[i];
            u1[i+2] = (float)a1[i];
            u2[i+2] = (float)a2[i];
        }
        bf16x8 ov;
        float v1o[8];
        #pragma unroll
        for (int i = 0; i < 8; ++i) {
            const float v0 = w0c*u0[i+2] + w0b*u0[i+1] + w0a*u0[i] + b0;
            const float v1 = w1c*u1[i+2] + w1b*u1[i+1] + w1a*u1[i] + b1;
            const float v2 = w2c*u2[i+2] + w2b*u2[i+1] + w2a*u2[i] + b2;
            ov[i] = (bf16_t)v0;
            v1o[i] = v2 * v1;
        }
        *(bf16x8*)(o0 + m0) = ov;
        *(float4*)(o1 + m0)     = make_float4(v1o[0], v1o[1], v1o[2], v1o[3]);
        *(float4*)(o1 + m0 + 4) = make_float4(v1o[4], v1o[5], v1o[6], v1o[7]);
    }
}

// ---------------------------------------------------------------------------
// Implicit filter MLP, phase 1: h2t (64, L).
// Block = 32 l-positions x 64 j, grid = 64 blocks.
// ---------------------------------------------------------------------------
__global__ __launch_bounds__(256) void filtermlp_kernel(
    const float* __restrict__ w1, const float* __restrict__ b1,
    const float* __restrict__ f1, const float* __restrict__ w2,
    const float* __restrict__ b2, const float* __restrict__ f2,
    float* __restrict__ h2t)
{
    __shared__ float w2s[64 * 64];      // 16 KB
    __shared__ float h1s[64][32];       // 8 KB, [j][l]
    const int tid = threadIdx.x;
    #pragma unroll
    for (int i = 0; i < 4; ++i)
        ((float4*)w2s)[tid + 256 * i] = ((const float4*)w2)[tid + 256 * i];

    const int l0 = blockIdx.x * 32;
    const int l  = tid & 31;
    const float fl = (float)(l0 + l);
    const float t   = fl * (1.0f / (float)(LL - 1));
    const float ang = 1e-4f * 6.283185307179586f * fl * (1.0f / (float)LL);
    const float z0 = t, z1 = cosf(ang), z2 = -sinf(ang);

    #pragma unroll
    for (int i = 0; i < 8; ++i) {
        const int j = (tid >> 5) + 8 * i;
        const float s = w1[j*3+0]*z0 + w1[j*3+1]*z1 + w1[j*3+2]*z2 + b1[j];
        h1s[j][l] = sinf(f1[j] * s);
    }
    __syncthreads();

    const int jb = (tid >> 5) * 8;
    float acc[8];
    #pragma unroll
    for (int i = 0; i < 8; ++i) acc[i] = b2[jb + i];
    #pragma unroll
    for (int jj = 0; jj < 64; jj += 4) {
        const float h0 = h1s[jj + 0][l];
        const float h1v = h1s[jj + 1][l];
        const float h2v = h1s[jj + 2][l];
        const float h3 = h1s[jj + 3][l];
        #pragma unroll
        for (int i = 0; i < 8; ++i) {
            const float4 wv = *(const float4*)&w2s[(jb + i) * 64 + jj];
            acc[i] += wv.x * h0 + wv.y * h1v + wv.z * h2v + wv.w * h3;
        }
    }
    #pragma unroll
    for (int i = 0; i < 8; ++i)
        h2t[(size_t)(jb + i) * LL + l0 + l] = sinf(f2[jb + i] * acc[i]);
}

// ---------------------------------------------------------------------------
// Implicit filter, phase 2: kfilt[d][l] = (w3[d,:] . h2t[:,l]) * exp(-t|delta_d|)
// ---------------------------------------------------------------------------
__global__ __launch_bounds__(256) void filtermod_kernel(
    const float* __restrict__ w3, const float* __restrict__ h2t,
    float* __restrict__ kfilt)
{
    __shared__ float w3s[32 * 64];      // 8 KB
    const int d0 = blockIdx.y * 32;
    const int l  = blockIdx.x * 256 + threadIdx.x;
    for (int i = threadIdx.x; i < 32 * 64; i += 256) w3s[i] = w3[d0 * 64 + i];
    __syncthreads();
    float acc[32] = {};
    for (int j = 0; j < 64; ++j) {
        const float v = h2t[j * LL + l];
        #pragma unroll
        for (int dd = 0; dd < 32; ++dd) acc[dd] += w3s[dd*64 + j] * v;
    }
    const float t = (float)l / (float)(LL - 1);
    const float min_decay = -3.0701134573253944f;   // ln(1e-2)/1.5
    const float max_decay = -15.350567286626972f;   // ln(1e-2)/0.3
    #pragma unroll
    for (int dd = 0; dd < 32; ++dd) {
        const int d = d0 + dd;
        const float delta = fabsf(min_decay + (max_decay - min_decay) * (float)d / (float)(DD - 1));
        kfilt[(size_t)d * LL + l] = acc[dd] * expf(-t * delta);
    }
}

// ---------------------------------------------------------------------------
// 4096-point complex Stockham RADIX-8 FFT, in-place in 32 KB LDS.
// ---------------------------------------------------------------------------
template<int SIGN>
__device__ __forceinline__ void fft4096_r8_ip(float2* __restrict__ buf)
{
    const float fs = (float)SIGN;
    const float RH = 0.7071067811865476f;   // sqrt(2)/2
    const int tid = threadIdx.x;            // 0..511
    #pragma unroll
    for (int t = 0; t < 4; ++t) {
        const int ls = 3 * t;               // log2(stride): 0,3,6,9
        const int s  = 1 << ls;
        const float theta = fs * 6.283185307179586f / (float)(4096 >> ls);
        float2 a[8];
        #pragma unroll
        for (int m = 0; m < 8; ++m) a[m] = buf[SWZ(tid + m * 512)];
        __syncthreads();
        const int p = tid >> ls;
        const int q = tid & (s - 1);
        float sn, cs;
        __sincosf(theta * (float)p, &sn, &cs);
        const float2 W1 = make_float2(cs, sn);
        const float2 W2 = cmul(W1, W1);
        const float2 W3 = cmul(W2, W1);
        const float2 W4 = cmul(W2, W2);
        const float2 W5 = cmul(W4, W1);
        const float2 W6 = cmul(W4, W2);
        const float2 W7 = cmul(W4, W3);
        const float2 es = cadd(a[0], a[4]), ed = csub(a[0], a[4]);
        const float2 fs2 = cadd(a[2], a[6]), fd = csub(a[2], a[6]);
        const float2 E0 = cadd(es, fs2);
        const float2 E1 = cadd(ed, cmuli(fd, fs));
        const float2 E2 = csub(es, fs2);
        const float2 E3 = csub(ed, cmuli(fd, fs));
        const float2 os = cadd(a[1], a[5]), od = csub(a[1], a[5]);
        const float2 gs = cadd(a[3], a[7]), gd = csub(a[3], a[7]);
        const float2 O0 = cadd(os, gs);
        const float2 O1 = cadd(od, cmuli(gd, fs));
        const float2 O2 = csub(os, gs);
        const float2 O3 = csub(od, cmuli(gd, fs));
        const float2 T0 = O0;
        const float2 T1 = make_float2(RH * (O1.x - fs * O1.y), RH * (fs * O1.x + O1.y));
        const float2 T2 = cmuli(O2, fs);
        const float2 T3 = make_float2(RH * (-O3.x - fs * O3.y), RH * (fs * O3.x - O3.y));
        const int o = q + (p << (ls + 3));
        buf[SWZ(o)]         = cadd(E0, T0);
        buf[SWZ(o + s)]     = cmul(W1, cadd(E1, T1));
        buf[SWZ(o + 2*s)]   = cmul(W2, cadd(E2, T2));
        buf[SWZ(o + 3*s)]   = cmul(W3, cadd(E3, T3));
        buf[SWZ(o + 4*s)]   = cmul(W4, csub(E0, T0));
        buf[SWZ(o + 5*s)]   = cmul(W5, csub(E1, T1));
        buf[SWZ(o + 6*s)]   = cmul(W6, csub(E2, T2));
        buf[SWZ(o + 7*s)]   = cmul(W7, csub(E3, T3));
        __syncthreads();
    }
}

// ---------------------------------------------------------------------------
// FFT of filter rows, two real rows per block (z = k_{2d} + i*k_{2d+1}).
// ---------------------------------------------------------------------------
__global__ __launch_bounds__(512, 4) void kfft_kernel(
    const float* __restrict__ kfilt, float2* __restrict__ Kf)
{
    __shared__ float2 fb[4096];           // 32 KB
    const int d0 = blockIdx.x * 2;
    const float* k0 = kfilt + (size_t)d0 * LL;
    const float* k1 = k0 + LL;
    const float inv = 1.0f / 4096.0f;
    const int tid = threadIdx.x;
    for (int i = tid; i < 2048; i += 512) {
        fb[SWZ(i)]        = make_float2(k0[i] * inv, k1[i] * inv);
        fb[SWZ(i + 2048)] = make_float2(0.f, 0.f);
    }
    __syncthreads();
    fft4096_r8_ip<-1>(fb);
    float2* o0 = Kf + (size_t)d0 * KF_STRIDE;
    float2* o1 = o0 + KF_STRIDE;
    for (int k = tid; k <= 2048; k += 512) {
        const float2 z1 = fb[SWZ(k)];
        const float2 z2 = fb[SWZ((4096 - k) & 4095)];
        o0[k] = make_float2(0.5f * (z1.x + z2.x), 0.5f * (z1.y - z2.y));
        o1[k] = make_float2(0.5f * (z1.y + z2.y), 0.5f * (z2.x - z1.x));
    }
}

// ---------------------------------------------------------------------------
// Long conv, two real rows per block: z = v1 + i*v2, filter k is REAL.
// ---------------------------------------------------------------------------
__global__ __launch_bounds__(512, 4) void fftconv_kernel(
    float* __restrict__ vio, const float2* __restrict__ Kf,
    const float* __restrict__ fbias)
{
    __shared__ float2 fb[4096];           // 32 KB
    const int blk = blockIdx.x;          // [0, 2048)
    const int d   = blk >> 1;
    float* v1 = vio + (size_t)(2 * blk) * LL;
    float* v2 = v1 + LL;
    const int tid = threadIdx.x;
    for (int i = tid; i < 2048; i += 512) {
        fb[SWZ(i)]        = make_float2(v1[i], v2[i]);
        fb[SWZ(i + 2048)] = make_float2(0.f, 0.f);
    }
    __syncthreads();
    fft4096_r8_ip<-1>(fb);
    const float2* kf = Kf + (size_t)d * KF_STRIDE;
    for (int i = tid; i < 4096; i += 512) {
        float2 k;
        if (i <= 2048) k = kf[i];
        else { const float2 t = kf[4096 - i]; k = make_float2(t.x, -t.y); }
        fb[SWZ(i)] = cmul(fb[SWZ(i)], k);
    }
    __syncthreads();
    fft4096_r8_ip<1>(fb);
    const float bias = fbias[d];
    for (int i = tid; i < 2048; i += 512) {
        const float2 zy = fb[SWZ(i)];
        v1[i] = zy.x + bias * v1[i];
        v2[i] = zy.y + bias * v2[i];
    }
}

// ---------------------------------------------------------------------------
// gated_bf16(B,L,D) = bf16( y(D,B,L) * x0t(D,B,L) )  -- LDS 32x32 transpose
// ---------------------------------------------------------------------------
__global__ __launch_bounds__(256) void gate_transpose_kernel(
    const float* __restrict__ y, const bf16_t* __restrict__ x0t,
    bf16_t* __restrict__ g)
{
    __shared__ float tile[32][33];
    const int b  = blockIdx.z;
    const int l0 = blockIdx.x * 32;
    const int d0 = blockIdx.y * 32;
    const int tx  = threadIdx.x & 31;
    const int tyb = threadIdx.x >> 5;    // 0..7
    #pragma unroll
    for (int i = 0; i < 4; ++i) {
        const int dy = tyb + i * 8;
        const size_t src = ((size_t)(d0 + dy) * BB + b) * LL + l0 + tx;
        tile[dy][tx] = y[src] * (float)x0t[src];
    }
    __syncthreads();
    #pragma unroll
    for (int i = 0; i < 4; ++i) {
        const int ly = tyb + i * 8;
        g[((size_t)(b * LL + l0 + ly)) * DD + d0 + tx] = (bf16_t)tile[tx][ly];
    }
}

// ---------------------------------------------------------------------------
// Launch
// ---------------------------------------------------------------------------
extern "C" void kernel_launch(void* const* d_in, const int* in_sizes, int n_in,
                              void* d_out, int out_size, void* d_ws, size_t ws_size,
                              hipStream_t stream)
{
    (void)in_sizes; (void)n_in; (void)out_size; (void)ws_size;
    const float* x   = (const float*)d_in[0];
    const float* nw0 = (const float*)d_in[1];
    const float* ipw = (const float*)d_in[2];
    const float* ipb = (const float*)d_in[3];
    const float* sfw = (const float*)d_in[4];
    const float* sfb = (const float*)d_in[5];
    const float* w1  = (const float*)d_in[6];
    const float* b1  = (const float*)d_in[7];
    const float* f1  = (const float*)d_in[8];
    const float* w2  = (const float*)d_in[9];
    const float* b2  = (const float*)d_in[10];
    const float* f2  = (const float*)d_in[11];
    const float* w3  = (const float*)d_in[12];
    const float* fbv = (const float*)d_in[13];
    const float* opw = (const float*)d_in[14];
    const float* opb = (const float*)d_in[15];
    const float* nw1 = (const float*)d_in[16];
    const float* fw1 = (const float*)d_in[17];
    const float* fb1 = (const float*)d_in[18];
    const float* fw2 = (const float*)d_in[19];
    const float* fb2 = (const float*)d_in[20];
    float* out = (float*)d_out;

    float* ws = (float*)d_ws;
    bf16_t* utb    = (bf16_t*)ws;
    bf16_t* gatedb = (bf16_t*)ws;                       // 8,388,608 bf16
    float*  h      = ws + 4194304;                      // 8,388,608 f
    bf16_t* midb   = (bf16_t*)(ws + 12582912);          // 16,777,216 bf16
    bf16_t* xnb    = (bf16_t*)(ws + 25165824);          // 8M bf16 (also hn later)
    bf16_t* x0tb   = (bf16_t*)(ws + 29360128);          // 8,388,608 bf16 (D,B,L)
    float*  vio    = ws + 37748736;                     // 8,388,608 f (D,B,L)
    float*  kfilt  = ws + 46137344;                     // 2,097,152 f
    float2* Kf     = (float2*)(ws + 48234496);          // 1024 x KF_STRIDE cplx
    bf16_t* ipwb   = (bf16_t*)(ws + 52445184);          // 3,145,728 bf16
    bf16_t* opwb   = ipwb + 3145728;                    // 1,048,576 bf16
    bf16_t* fw1b   = opwb + 1048576;                    // 2,097,152 bf16
    bf16_t* fw2b   = fw1b + 2097152;                    // 2,097,152 bf16
    float*  h2t    = ws + 56639488;                     // (64, L) = 131,072 f

    // 0. weight casts (single launch, region-dispatched)
    cast_all_kernel<<<8192, 256, 0, stream>>>(ipw, opw, fw1, fw2,
                                              ipwb, opwb, fw1b, fw2b);
    // 1. implicit filter: MLP phase (h2t), modulation phase (kfilt), FFT (Kf)
    filtermlp_kernel<<<LL/32, 256, 0, stream>>>(w1, b1, f1, w2, b2, f2, h2t);
    filtermod_kernel<<<dim3(LL/256, DD/32), 256, 0, stream>>>(w3, h2t, kfilt);
    kfft_kernel<<<DD/2, 512, 0, stream>>>(kfilt, Kf);
    // 2. xn = bf16(rmsnorm(x, norm_in_w))
    rmsnorm_bf16_kernel<<<MM, 256, 0, stream>>>(x, nw0, xnb);
    // 3. u_t = in_proj_w @ xn^T + b (transposed output, bf16)
    gemm_mfma_kernel<0, true, true><<<dim3(MM/128, 3072/128), 512, 0, stream>>>(
        ipwb, xnb, ipb, nullptr, nullptr, utb, 3*DD, MM, DD);
    // 4. short filter -> x0t (D,B,L) bf16, vin (D,B,L) fp32
    shortfilter_kernel<<<DD, 256, 0, stream>>>(utb, sfw, sfb, x0tb, vio);
    // 5. vio <- causal_conv(vio, k) + filter_bias * vio   (2 rows per block)
    fftconv_kernel<<<BB*DD/2, 512, 0, stream>>>(vio, Kf, fbv);
    // 6. gated_bf16(B,L,D) = y * x0
    gate_transpose_kernel<<<dim3(LL/32, DD/32, BB), 256, 0, stream>>>(vio, x0tb, gatedb);
    // 7. h = gated @ out_proj_w^T + b + x   (M=8192, N=1024, K=1024)
    gemm_mfma_kernel<1, false><<<dim3(DD/128, MM/128), 512, 0, stream>>>(
        gatedb, opwb, opb, x, h, nullptr, MM, DD, DD);
    // 8. hn = bf16(rmsnorm(h, norm_w))
    rmsnorm_bf16_kernel<<<MM, 256, 0, stream>>>(h, nw1, xnb);
    // 9. mid = bf16(gelu(hn @ ffn_w1^T + b))  (M=8192, N=2048, K=1024)
    gemm_mfma_kernel<2, true><<<dim3(2*DD/128, MM/128), 512, 0, stream>>>(
        xnb, fw1b, fb1, nullptr, nullptr, midb, MM, 2*DD, DD);
    // 10. out = mid @ ffn_w2^T + b + h      (M=8192, N=1024, K=2048)
    gemm_mfma_kernel<1, false><<<dim3(DD/128, MM/128), 512, 0, stream>>>(
        midb, fw2b, fb2, h, out, nullptr, MM, DD, 2*DD);
}